// Round 3
// baseline (2381.536 us; speedup 1.0000x reference)
//
#include <hip/hip_runtime.h>

#define NN 50000
#define ND (NN * 128)

__device__ __forceinline__ float b2f(unsigned short u) {
    union { unsigned int i; float f; } v; v.i = ((unsigned int)u) << 16; return v.f;
}

// ---- dtype detection: flags[0]=1 if floats are fp32; flags[1]=1 if edges are int32 ----
__global__ __launch_bounds__(256) void detect(
    const unsigned short* __restrict__ feat_u, const unsigned int* __restrict__ ei_u,
    int* __restrict__ flags)
{
    int tid = threadIdx.x;
    int f32hit = 0;
    for (int i = tid; i < 8192; i += 256) {
        unsigned e = (feat_u[i] >> 7) & 0xFFu;   // bf16 exponent field
        if (e >= 0xC0u) f32hit = 1;              // |v| >= 2^65: impossible for bf16 N(0,1)
    }
    int i32hit = 0;
    for (int i = tid; i < 4096; i += 256) {
        if (ei_u[2 * i + 1] != 0u) i32hit = 1;   // int64 LE high words are all 0 (vals < 50000)
    }
    if (f32hit) atomicOr(&flags[0], 1);
    if (i32hit) atomicOr(&flags[1], 1);
}

// ---- canonicalize float input (bf16 or fp32) to fp32 ----
__global__ __launch_bounds__(256) void convertN(
    const void* __restrict__ in, float* __restrict__ out, int n, const int* __restrict__ flags)
{
    int i = blockIdx.x * 256 + threadIdx.x;
    if (i >= n) return;
    out[i] = flags[0] ? ((const float*)in)[i] : b2f(((const unsigned short*)in)[i]);
}

// ---- 128x128 GEMM: Out[n,128] = A[n,128] @ W[128,128] + b (fp32 out) ----
__global__ __launch_bounds__(256) void gemm128(
    const float* __restrict__ A, const float* __restrict__ W,
    const float* __restrict__ bias, float* __restrict__ Out, int nRows)
{
    __shared__ float Wl[128 * 128];
    __shared__ float Ar[256];
    int tid = threadIdx.x;
    for (int i = tid; i < 128 * 128; i += 256) Wl[i] = W[i];
    int col = tid & 127;
    int rh  = tid >> 7;
    float b = bias[col];
    int rowBase = blockIdx.x * 32;
    __syncthreads();
    for (int p = 0; p < 16; ++p) {
        int lr = rowBase + p * 2 + rh;
        if (lr < nRows) Ar[tid] = A[lr * 128 + col];
        __syncthreads();
        if (lr < nRows) {
            float acc = b;
            #pragma unroll
            for (int k = 0; k < 128; ++k)
                acc = fmaf(Ar[rh * 128 + k], Wl[k * 128 + col], acc);
            Out[lr * 128 + col] = acc;
        }
        __syncthreads();
    }
}

// ---- channel-normalize (K=4, dd=32) + init next scatter target ----
// NormOut = normalize(In) (safe in-place); InitOut = CopySrc ? CopySrc : normalized
__global__ __launch_bounds__(256) void norm_init(
    const float* __restrict__ In, float* __restrict__ NormOut,
    float* __restrict__ InitOut, const float* __restrict__ CopySrc)
{
    int node = blockIdx.x * 4 + (threadIdx.x >> 6);
    if (node >= NN) return;
    int lane = threadIdx.x & 63;             // elems 2*lane, 2*lane+1; 16 lanes = one channel
    float2 v = ((const float2*)(In + node * 128))[lane];
    float ss = v.x * v.x + v.y * v.y;
    ss += __shfl_xor(ss, 1);
    ss += __shfl_xor(ss, 2);
    ss += __shfl_xor(ss, 4);
    ss += __shfl_xor(ss, 8);
    float scale = 1.0f / fmaxf(sqrtf(ss), 1e-12f);
    float2 o; o.x = v.x * scale; o.y = v.y * scale;
    ((float2*)(NormOut + node * 128))[lane] = o;
    if (CopySrc)
        ((float2*)(InitOut + node * 128))[lane] = ((const float2*)(CopySrc + node * 128))[lane];
    else
        ((float2*)(InitOut + node * 128))[lane] = o;
}

// ---- routing edge kernel: one 32-lane half-wave per edge ----
__global__ __launch_bounds__(256) void edge_route(
    const void* __restrict__ eiRaw, const float* __restrict__ CN,
    const float* __restrict__ XN, float* __restrict__ CT, int m,
    const int* __restrict__ flags)
{
    int e = blockIdx.x * 8 + (threadIdx.x >> 5);
    if (e >= m) return;
    int a = threadIdx.x & 31;
    int src, trg;
    if (flags[1]) {
        const int* p = (const int*)eiRaw;
        src = p[e]; trg = p[m + e];
    } else {
        const long long* p = (const long long*)eiRaw;
        src = (int)p[e]; trg = (int)p[m + e];
    }
    src = min(max(src, 0), NN - 1);
    trg = min(max(trg, 0), NN - 1);
    // s_a = sum_j cn[trg][4a+j]  (reshape-not-transpose grouping)
    float4 c4 = ((const float4*)(CN + (long)trg * 128))[a];
    float s = c4.x + c4.y + c4.z + c4.w;
    // z_k[a] = xn[src][32k+a]
    const float* zp = XN + (long)src * 128 + a;
    float z0 = zp[0], z1 = zp[32], z2 = zp[64], z3 = zp[96];
    float p0 = z0 * s, p1 = z1 * s, p2 = z2 * s, p3 = z3 * s;
    #pragma unroll
    for (int msk = 1; msk <= 16; msk <<= 1) {
        p0 += __shfl_xor(p0, msk);
        p1 += __shfl_xor(p1, msk);
        p2 += __shfl_xor(p2, msk);
        p3 += __shfl_xor(p3, msk);
    }
    float mx = fmaxf(fmaxf(p0, p1), fmaxf(p2, p3));
    float e0 = __expf(p0 - mx), e1 = __expf(p1 - mx);
    float e2 = __expf(p2 - mx), e3 = __expf(p3 - mx);
    float inv = 1.0f / (e0 + e1 + e2 + e3);
    float* ct = CT + (long)trg * 128 + a;
    unsafeAtomicAdd(ct +  0, e0 * inv * z0);
    unsafeAtomicAdd(ct + 32, e1 * inv * z1);
    unsafeAtomicAdd(ct + 64, e2 * inv * z2);
    unsafeAtomicAdd(ct + 96, e3 * inv * z3);
}

extern "C" void kernel_launch(void* const* d_in, const int* in_sizes, int n_in,
                              void* d_out, int out_size, void* d_ws, size_t ws_size,
                              hipStream_t stream) {
    const void* feat  = d_in[0];
    const void* ei    = d_in[1];
    const void* lin_w = d_in[2];
    const void* lin_b = d_in[3];
    const void* mlp_w = d_in[4];
    const void* mlp_b = d_in[5];
    float* out = (float*)d_out;               // fp32 outputs: [out(N,128) | x(N,128)]

    const int m = in_sizes[1] / 2;            // 800000 edges

    // workspace layout
    char* wsB = (char*)d_ws;
    int*   flags = (int*)wsB;                                  // 2 ints
    float* Wlin  = (float*)(wsB + 256);                        // 16384
    float* blin  = Wlin + 16384;                               // 128
    float* Wmlp  = blin + 128;                                 // 16384
    float* bmlp  = Wmlp + 16384;                               // 128
    float* B0    = bmlp + 128;                                 // 3 x ND floats
    float* B1    = B0 + ND;
    float* B2    = B1 + ND;

    hipMemsetAsync(flags, 0, 8, stream);
    detect<<<1, 256, 0, stream>>>((const unsigned short*)feat, (const unsigned int*)ei, flags);

    // canonicalize float inputs to fp32
    convertN<<<(ND + 255) / 256, 256, 0, stream>>>(feat, B1, ND, flags);
    convertN<<<64, 256, 0, stream>>>(lin_w, Wlin, 16384, flags);
    convertN<<<1, 128, 0, stream>>>(lin_b, blin, 128, flags);
    convertN<<<64, 256, 0, stream>>>(mlp_w, Wmlp, 16384, flags);
    convertN<<<1, 128, 0, stream>>>(mlp_b, bmlp, 128, flags);

    const int gemmBlocks = (NN + 31) / 32;
    const int normBlocks = (NN + 3) / 4;
    const int edgeBlocks = (m + 7) / 8;

    // x = feat @ lin_w + lin_b   (B1 -> B0)
    gemm128<<<gemmBlocks, 256, 0, stream>>>(B1, Wlin, blin, B0, NN);

    // layer 1: xn in B0, rotate B1/B2
    norm_init<<<normBlocks, 256, 0, stream>>>(B0, B0, B1, nullptr);       // B0=XN, B1=XN
    edge_route<<<edgeBlocks, 256, 0, stream>>>(ei, B0, B0, B1, m, flags); // c1 -> B1
    norm_init<<<normBlocks, 256, 0, stream>>>(B1, B1, B2, B0);            // B1=norm(c1), B2=XN
    edge_route<<<edgeBlocks, 256, 0, stream>>>(ei, B1, B0, B2, m, flags); // c2 -> B2
    norm_init<<<normBlocks, 256, 0, stream>>>(B2, B2, B1, B0);            // B2=norm(c2), B1=XN
    edge_route<<<edgeBlocks, 256, 0, stream>>>(ei, B2, B0, B1, m, flags); // c3 -> B1 (layer out)

    // layer 2: xn in B1, rotate B2/B0
    norm_init<<<normBlocks, 256, 0, stream>>>(B1, B1, B2, nullptr);       // B1=XN2, B2=XN2
    edge_route<<<edgeBlocks, 256, 0, stream>>>(ei, B1, B1, B2, m, flags); // c1 -> B2
    norm_init<<<normBlocks, 256, 0, stream>>>(B2, B2, B0, B1);            // B2=norm(c1), B0=XN2
    edge_route<<<edgeBlocks, 256, 0, stream>>>(ei, B2, B1, B0, m, flags); // c2 -> B0
    norm_init<<<normBlocks, 256, 0, stream>>>(B0, B0, B2, B1);            // B0=norm(c2), B2=XN2
    edge_route<<<edgeBlocks, 256, 0, stream>>>(ei, B0, B1, B2, m, flags); // final x -> B2

    // out = x @ mlp_w + mlp_b (fp32); second output = x (fp32, d2d copy)
    gemm128<<<gemmBlocks, 256, 0, stream>>>(B2, Wmlp, bmlp, out, NN);
    hipMemcpyAsync(out + ND, B2, (size_t)ND * sizeof(float),
                   hipMemcpyDeviceToDevice, stream);
}

// Round 4
// 1058.349 us; speedup vs baseline: 2.2502x; 2.2502x over previous
//
#include <hip/hip_runtime.h>

#define NN 50000
#define ND (NN * 128)
#define SCAN_B 49   // ceil(NN / 1024)

__device__ __forceinline__ float b2f(unsigned short u) {
    union { unsigned int i; float f; } v; v.i = ((unsigned int)u) << 16; return v.f;
}

// ---- dtype detection: flags[0]=1 if floats are fp32; flags[1]=1 if edges are int32 ----
__global__ __launch_bounds__(256) void detect(
    const unsigned short* __restrict__ feat_u, const unsigned int* __restrict__ ei_u,
    int* __restrict__ flags)
{
    int tid = threadIdx.x;
    int f32hit = 0;
    for (int i = tid; i < 8192; i += 256) {
        unsigned e = (feat_u[i] >> 7) & 0xFFu;
        if (e >= 0xC0u) f32hit = 1;              // |v| >= 2^65: impossible for bf16 N(0,1)
    }
    int i32hit = 0;
    for (int i = tid; i < 4096; i += 256) {
        if (ei_u[2 * i + 1] != 0u) i32hit = 1;   // int64 LE high words all 0 (vals < 50000)
    }
    if (f32hit) atomicOr(&flags[0], 1);
    if (i32hit) atomicOr(&flags[1], 1);
}

// ---- canonicalize float input (bf16 or fp32) to fp32 ----
__global__ __launch_bounds__(256) void convertN(
    const void* __restrict__ in, float* __restrict__ out, int n, const int* __restrict__ flags)
{
    int i = blockIdx.x * 256 + threadIdx.x;
    if (i >= n) return;
    out[i] = flags[0] ? ((const float*)in)[i] : b2f(((const unsigned short*)in)[i]);
}

// ---- extract int32 src/trg + degree histogram ----
__global__ __launch_bounds__(256) void conv_hist(
    const void* __restrict__ eiRaw, int* __restrict__ srcA, int* __restrict__ trgA,
    int* __restrict__ deg, int m, const int* __restrict__ flags)
{
    int e = blockIdx.x * 256 + threadIdx.x;
    if (e >= m) return;
    int src, trg;
    if (flags[1]) { const int* p = (const int*)eiRaw; src = p[e]; trg = p[m + e]; }
    else { const long long* p = (const long long*)eiRaw; src = (int)p[e]; trg = (int)p[m + e]; }
    src = min(max(src, 0), NN - 1);
    trg = min(max(trg, 0), NN - 1);
    srcA[e] = src; trgA[e] = trg;
    atomicAdd(&deg[trg], 1);
}

// ---- exclusive scan of deg[NN] -> rowStart[NN] (3-kernel hierarchical) ----
__global__ __launch_bounds__(256) void scan1(
    const int* __restrict__ deg, int* __restrict__ rowStart, int* __restrict__ blkSum)
{
    __shared__ int lds[256];
    int blk = blockIdx.x, tid = threadIdx.x;
    int base = blk * 1024 + tid * 4;
    int v[4]; int s = 0;
    #pragma unroll
    for (int j = 0; j < 4; ++j) { int idx = base + j; v[j] = (idx < NN) ? deg[idx] : 0; s += v[j]; }
    lds[tid] = s; __syncthreads();
    for (int off = 1; off < 256; off <<= 1) {
        int x = (tid >= off) ? lds[tid - off] : 0;
        __syncthreads();
        lds[tid] += x;
        __syncthreads();
    }
    int excl = lds[tid] - s;
    if (tid == 255) blkSum[blk] = lds[tid];
    int run = excl;
    #pragma unroll
    for (int j = 0; j < 4; ++j) { int idx = base + j; if (idx < NN) rowStart[idx] = run; run += v[j]; }
}
__global__ __launch_bounds__(64) void scan2(
    int* __restrict__ blkSum, int* __restrict__ blkOff, int* __restrict__ rowStart, int m)
{
    int lane = threadIdx.x;
    int orig = (lane < SCAN_B) ? blkSum[lane] : 0;
    int v = orig;
    for (int off = 1; off < 64; off <<= 1) {
        int x = __shfl_up(v, off);
        if (lane >= off) v += x;
    }
    if (lane < SCAN_B) blkOff[lane] = v - orig;   // exclusive
    if (lane == 0) rowStart[NN] = m;
}
__global__ __launch_bounds__(256) void scan3(int* __restrict__ rowStart, const int* __restrict__ blkOff)
{
    int base = blockIdx.x * 1024 + threadIdx.x * 4;
    int off = blkOff[blockIdx.x];
    #pragma unroll
    for (int j = 0; j < 4; ++j) { int idx = base + j; if (idx < NN) rowStart[idx] += off; }
}

// ---- scatter edges into CSR bins ----
__global__ __launch_bounds__(256) void scatter_csr(
    const int* __restrict__ srcA, const int* __restrict__ trgA,
    int* __restrict__ cursor, int* __restrict__ eSrc, int m)
{
    int e = blockIdx.x * 256 + threadIdx.x;
    if (e >= m) return;
    int pos = atomicAdd(&cursor[trgA[e]], 1);
    eSrc[pos] = srcA[e];
}

// ---- 128x128 GEMM: Out[n,128] = A[n,128] @ W[128,128] + b ----
__global__ __launch_bounds__(256) void gemm128(
    const float* __restrict__ A, const float* __restrict__ W,
    const float* __restrict__ bias, float* __restrict__ Out, int nRows)
{
    __shared__ float Wl[128 * 128];
    __shared__ float Ar[256];
    int tid = threadIdx.x;
    for (int i = tid; i < 128 * 128; i += 256) Wl[i] = W[i];
    int col = tid & 127;
    int rh  = tid >> 7;
    float b = bias[col];
    int rowBase = blockIdx.x * 32;
    __syncthreads();
    for (int p = 0; p < 16; ++p) {
        int lr = rowBase + p * 2 + rh;
        if (lr < nRows) Ar[tid] = A[lr * 128 + col];
        __syncthreads();
        if (lr < nRows) {
            float acc = b;
            #pragma unroll
            for (int k = 0; k < 128; ++k)
                acc = fmaf(Ar[rh * 128 + k], Wl[k * 128 + col], acc);
            Out[lr * 128 + col] = acc;
        }
        __syncthreads();
    }
}

// ---- channel-normalize (K=4, dd=32) + per-node S (s_a = sum_j cn[4a+j]) ----
__global__ __launch_bounds__(256) void norm_S(
    const float* __restrict__ In, float* __restrict__ NormOut, float* __restrict__ SOut)
{
    int node = blockIdx.x * 4 + (threadIdx.x >> 6);
    if (node >= NN) return;
    int lane = threadIdx.x & 63;             // elems 2*lane, 2*lane+1; 16 lanes = one channel
    float2 v = ((const float2*)(In + (long)node * 128))[lane];
    float ss = v.x * v.x + v.y * v.y;
    ss += __shfl_xor(ss, 1);
    ss += __shfl_xor(ss, 2);
    ss += __shfl_xor(ss, 4);
    ss += __shfl_xor(ss, 8);
    float scale = 1.0f / fmaxf(sqrtf(ss), 1e-12f);
    float2 o; o.x = v.x * scale; o.y = v.y * scale;
    ((float2*)(NormOut + (long)node * 128))[lane] = o;
    float t = o.x + o.y;                     // s_a = cn[4a]+cn[4a+1]+cn[4a+2]+cn[4a+3]
    t += __shfl_xor(t, 1);
    if (!(lane & 1)) SOut[node * 32 + (lane >> 1)] = t;
}

// ---- node-centric routing: one wave per target node, 2 edges in flight ----
__global__ __launch_bounds__(256) void route_nodes(
    const int* __restrict__ rowStart, const int* __restrict__ eSrc,
    const float* __restrict__ S, const float* __restrict__ XN,
    float* __restrict__ CT)
{
    int node = blockIdx.x * 4 + (threadIdx.x >> 6);
    if (node >= NN) return;
    int lane = threadIdx.x & 63;
    int half = lane >> 5;                    // which of the 2 edge slots
    int a = lane & 31;                       // dd index
    float s = S[node * 32 + a];
    float a0, a1, a2, a3;
    if (half == 0) {                         // residual xn[trg] folded into init
        const float* xp = XN + (long)node * 128 + a;
        a0 = xp[0]; a1 = xp[32]; a2 = xp[64]; a3 = xp[96];
    } else { a0 = a1 = a2 = a3 = 0.f; }
    int beg = rowStart[node], end = rowStart[node + 1];
    for (int i = beg + half; i < end; i += 2) {
        int src = eSrc[i];
        const float* zp = XN + (long)src * 128 + a;
        float z0 = zp[0], z1 = zp[32], z2 = zp[64], z3 = zp[96];
        float p0 = z0 * s, p1 = z1 * s, p2 = z2 * s, p3 = z3 * s;
        #pragma unroll
        for (int msk = 1; msk <= 16; msk <<= 1) {   // reduce within 32-lane half
            p0 += __shfl_xor(p0, msk);
            p1 += __shfl_xor(p1, msk);
            p2 += __shfl_xor(p2, msk);
            p3 += __shfl_xor(p3, msk);
        }
        float mx = fmaxf(fmaxf(p0, p1), fmaxf(p2, p3));
        float e0 = __expf(p0 - mx), e1 = __expf(p1 - mx);
        float e2 = __expf(p2 - mx), e3 = __expf(p3 - mx);
        float inv = 1.0f / (e0 + e1 + e2 + e3);
        a0 = fmaf(e0 * inv, z0, a0);
        a1 = fmaf(e1 * inv, z1, a1);
        a2 = fmaf(e2 * inv, z2, a2);
        a3 = fmaf(e3 * inv, z3, a3);
    }
    a0 += __shfl_xor(a0, 32);                // combine the two halves
    a1 += __shfl_xor(a1, 32);
    a2 += __shfl_xor(a2, 32);
    a3 += __shfl_xor(a3, 32);
    if (half == 0) {
        float* cp = CT + (long)node * 128 + a;
        cp[0] = a0; cp[32] = a1; cp[64] = a2; cp[96] = a3;
    }
}

extern "C" void kernel_launch(void* const* d_in, const int* in_sizes, int n_in,
                              void* d_out, int out_size, void* d_ws, size_t ws_size,
                              hipStream_t stream) {
    const void* feat  = d_in[0];
    const void* ei    = d_in[1];
    const void* lin_w = d_in[2];
    const void* lin_b = d_in[3];
    const void* mlp_w = d_in[4];
    const void* mlp_b = d_in[5];
    float* out = (float*)d_out;               // [out(N,128) | x(N,128)] fp32

    const int m = in_sizes[1] / 2;            // 800000 edges

    // ---- workspace layout (floats first for 16B alignment) ----
    char* wsB = (char*)d_ws;
    int*   flags = (int*)wsB;                                  // 256 B slot
    float* Wlin  = (float*)(wsB + 256);                        // 16384
    float* blin  = Wlin + 16384;                               // 128
    float* Wmlp  = blin + 128;                                 // 16384
    float* bmlp  = Wmlp + 16384;                               // 128
    float* S     = bmlp + 128;                                 // NN*32
    float* B0    = S + NN * 32;                                // ND
    float* B1    = B0 + ND;                                    // ND
    float* B2    = B1 + ND;                                    // ND
    int*   srcA  = (int*)(B2 + ND);                            // m
    int*   trgA  = srcA + m;                                   // m
    int*   eSrc  = trgA + m;                                   // m
    int*   deg   = eSrc + m;                                   // NN
    int*   rowStart = deg + NN;                                // NN+1
    int*   cursor   = rowStart + NN + 1;                       // NN
    int*   blkSum   = cursor + NN;                             // 64
    int*   blkOff   = blkSum + 64;                             // 64

    hipMemsetAsync(flags, 0, 8, stream);
    hipMemsetAsync(deg, 0, NN * sizeof(int), stream);
    detect<<<1, 256, 0, stream>>>((const unsigned short*)feat, (const unsigned int*)ei, flags);

    // canonicalize float inputs
    convertN<<<(ND + 255) / 256, 256, 0, stream>>>(feat, B1, ND, flags);
    convertN<<<64, 256, 0, stream>>>(lin_w, Wlin, 16384, flags);
    convertN<<<1, 128, 0, stream>>>(lin_b, blin, 128, flags);
    convertN<<<64, 256, 0, stream>>>(mlp_w, Wmlp, 16384, flags);
    convertN<<<1, 128, 0, stream>>>(mlp_b, bmlp, 128, flags);

    // build CSR by target
    const int edgeBlocks = (m + 255) / 256;
    conv_hist<<<edgeBlocks, 256, 0, stream>>>(ei, srcA, trgA, deg, m, flags);
    scan1<<<SCAN_B, 256, 0, stream>>>(deg, rowStart, blkSum);
    scan2<<<1, 64, 0, stream>>>(blkSum, blkOff, rowStart, m);
    scan3<<<SCAN_B, 256, 0, stream>>>(rowStart, blkOff);
    hipMemcpyAsync(cursor, rowStart, NN * sizeof(int), hipMemcpyDeviceToDevice, stream);
    scatter_csr<<<edgeBlocks, 256, 0, stream>>>(srcA, trgA, cursor, eSrc, m);

    const int gemmBlocks = (NN + 31) / 32;
    const int nodeBlocks = (NN + 3) / 4;

    // x = feat @ lin_w + lin_b   (B1 -> B0)
    gemm128<<<gemmBlocks, 256, 0, stream>>>(B1, Wlin, blin, B0, NN);

    // layer 1: X=B0, XN=B1, C=B2
    norm_S<<<nodeBlocks, 256, 0, stream>>>(B0, B1, S);
    route_nodes<<<nodeBlocks, 256, 0, stream>>>(rowStart, eSrc, S, B1, B2);
    norm_S<<<nodeBlocks, 256, 0, stream>>>(B2, B2, S);
    route_nodes<<<nodeBlocks, 256, 0, stream>>>(rowStart, eSrc, S, B1, B2);
    norm_S<<<nodeBlocks, 256, 0, stream>>>(B2, B2, S);
    route_nodes<<<nodeBlocks, 256, 0, stream>>>(rowStart, eSrc, S, B1, B2);

    // layer 2: X=B2, XN=B0, C=B1
    norm_S<<<nodeBlocks, 256, 0, stream>>>(B2, B0, S);
    route_nodes<<<nodeBlocks, 256, 0, stream>>>(rowStart, eSrc, S, B0, B1);
    norm_S<<<nodeBlocks, 256, 0, stream>>>(B1, B1, S);
    route_nodes<<<nodeBlocks, 256, 0, stream>>>(rowStart, eSrc, S, B0, B1);
    norm_S<<<nodeBlocks, 256, 0, stream>>>(B1, B1, S);
    route_nodes<<<nodeBlocks, 256, 0, stream>>>(rowStart, eSrc, S, B0, B1);

    // out = x @ mlp_w + mlp_b; second output = x
    gemm128<<<gemmBlocks, 256, 0, stream>>>(B1, Wmlp, bmlp, out, NN);
    hipMemcpyAsync(out + ND, B1, (size_t)ND * sizeof(float),
                   hipMemcpyDeviceToDevice, stream);
}

// Round 5
// 654.172 us; speedup vs baseline: 3.6405x; 1.6178x over previous
//
#include <hip/hip_runtime.h>

#define NN 50000
#define ND (NN * 128)
#define SCAN_B 49   // ceil(NN / 1024)

__device__ __forceinline__ float b2f(unsigned short u) {
    union { unsigned int i; float f; } v; v.i = ((unsigned int)u) << 16; return v.f;
}

// DPP all-reduce within 16-lane rows: runs on VALU pipe, no LDS traffic.
template<int CTRL>
__device__ __forceinline__ float dpp_add(float v) {
    int s = __builtin_amdgcn_update_dpp(0, __float_as_int(v), CTRL, 0xF, 0xF, true);
    return v + __int_as_float(s);
}
__device__ __forceinline__ float red16(float v) {
    v = dpp_add<0xB1>(v);    // quad_perm [1,0,3,2]  (xor 1)
    v = dpp_add<0x4E>(v);    // quad_perm [2,3,0,1]  (xor 2)
    v = dpp_add<0x124>(v);   // row_ror:4
    v = dpp_add<0x128>(v);   // row_ror:8  -> every lane holds 16-lane sum
    return v;
}

// ---- dtype detection: flags[0]=1 if floats are fp32; flags[1]=1 if edges are int32 ----
__global__ __launch_bounds__(256) void detect(
    const unsigned short* __restrict__ feat_u, const unsigned int* __restrict__ ei_u,
    int* __restrict__ flags)
{
    int tid = threadIdx.x;
    int f32hit = 0;
    for (int i = tid; i < 8192; i += 256) {
        unsigned e = (feat_u[i] >> 7) & 0xFFu;
        if (e >= 0xC0u) f32hit = 1;
    }
    int i32hit = 0;
    for (int i = tid; i < 4096; i += 256) {
        if (ei_u[2 * i + 1] != 0u) i32hit = 1;
    }
    if (f32hit) atomicOr(&flags[0], 1);
    if (i32hit) atomicOr(&flags[1], 1);
}

// ---- canonicalize float input (bf16 or fp32) to fp32 ----
__global__ __launch_bounds__(256) void convertN(
    const void* __restrict__ in, float* __restrict__ out, int n, const int* __restrict__ flags)
{
    int i = blockIdx.x * 256 + threadIdx.x;
    if (i >= n) return;
    out[i] = flags[0] ? ((const float*)in)[i] : b2f(((const unsigned short*)in)[i]);
}

// ---- extract int32 src/trg + degree histogram ----
__global__ __launch_bounds__(256) void conv_hist(
    const void* __restrict__ eiRaw, int* __restrict__ srcA, int* __restrict__ trgA,
    int* __restrict__ deg, int m, const int* __restrict__ flags)
{
    int e = blockIdx.x * 256 + threadIdx.x;
    if (e >= m) return;
    int src, trg;
    if (flags[1]) { const int* p = (const int*)eiRaw; src = p[e]; trg = p[m + e]; }
    else { const long long* p = (const long long*)eiRaw; src = (int)p[e]; trg = (int)p[m + e]; }
    src = min(max(src, 0), NN - 1);
    trg = min(max(trg, 0), NN - 1);
    srcA[e] = src; trgA[e] = trg;
    atomicAdd(&deg[trg], 1);
}

// ---- exclusive scan of deg[NN] -> rowStart[NN] ----
__global__ __launch_bounds__(256) void scan1(
    const int* __restrict__ deg, int* __restrict__ rowStart, int* __restrict__ blkSum)
{
    __shared__ int lds[256];
    int blk = blockIdx.x, tid = threadIdx.x;
    int base = blk * 1024 + tid * 4;
    int v[4]; int s = 0;
    #pragma unroll
    for (int j = 0; j < 4; ++j) { int idx = base + j; v[j] = (idx < NN) ? deg[idx] : 0; s += v[j]; }
    lds[tid] = s; __syncthreads();
    for (int off = 1; off < 256; off <<= 1) {
        int x = (tid >= off) ? lds[tid - off] : 0;
        __syncthreads();
        lds[tid] += x;
        __syncthreads();
    }
    int excl = lds[tid] - s;
    if (tid == 255) blkSum[blk] = lds[tid];
    int run = excl;
    #pragma unroll
    for (int j = 0; j < 4; ++j) { int idx = base + j; if (idx < NN) rowStart[idx] = run; run += v[j]; }
}
__global__ __launch_bounds__(64) void scan2(
    int* __restrict__ blkSum, int* __restrict__ blkOff, int* __restrict__ rowStart, int m)
{
    int lane = threadIdx.x;
    int orig = (lane < SCAN_B) ? blkSum[lane] : 0;
    int v = orig;
    for (int off = 1; off < 64; off <<= 1) {
        int x = __shfl_up(v, off);
        if (lane >= off) v += x;
    }
    if (lane < SCAN_B) blkOff[lane] = v - orig;
    if (lane == 0) rowStart[NN] = m;
}
__global__ __launch_bounds__(256) void scan3(int* __restrict__ rowStart, const int* __restrict__ blkOff)
{
    int base = blockIdx.x * 1024 + threadIdx.x * 4;
    int off = blkOff[blockIdx.x];
    #pragma unroll
    for (int j = 0; j < 4; ++j) { int idx = base + j; if (idx < NN) rowStart[idx] += off; }
}

// ---- scatter edges into CSR bins ----
__global__ __launch_bounds__(256) void scatter_csr(
    const int* __restrict__ srcA, const int* __restrict__ trgA,
    int* __restrict__ cursor, int* __restrict__ eSrc, int m)
{
    int e = blockIdx.x * 256 + threadIdx.x;
    if (e >= m) return;
    int pos = atomicAdd(&cursor[trgA[e]], 1);
    eSrc[pos] = srcA[e];
}

// ---- GEMM: Out[n,128] = A[n,128] @ W[128,128] + b ; 4x4 register tile/thread ----
// Optional Copy: write-through of A (fuses the x-output copy into gemm2 staging).
__global__ __launch_bounds__(256) void gemm128(
    const float* __restrict__ A, const float* __restrict__ W,
    const float* __restrict__ bias, float* __restrict__ Out,
    float* __restrict__ Copy, int nRows)
{
    __shared__ float Wl[128 * 128];   // 64 KB
    __shared__ float As[32 * 128];    // 16 KB
    int tid = threadIdx.x;
    int cg = tid & 31;                // col group: cols 4cg..4cg+3
    int rg = tid >> 5;                // row group: rows rg*4..rg*4+3 (of 32)
    int rowBase = blockIdx.x * 32;

    for (int i = tid * 4; i < 128 * 128; i += 1024)
        *(float4*)&Wl[i] = *(const float4*)&W[i];

    #pragma unroll
    for (int r = 0; r < 4; ++r) {
        int lrow = r * 8 + (tid >> 5);
        int row = rowBase + lrow;
        float4 v = make_float4(0.f, 0.f, 0.f, 0.f);
        if (row < nRows) v = *(const float4*)&A[(long)row * 128 + cg * 4];
        *(float4*)&As[lrow * 128 + cg * 4] = v;
        if (Copy && row < nRows) *(float4*)&Copy[(long)row * 128 + cg * 4] = v;
    }
    float4 bb = *(const float4*)&bias[cg * 4];
    __syncthreads();

    float acc[4][4];
    #pragma unroll
    for (int i = 0; i < 4; ++i) { acc[i][0]=bb.x; acc[i][1]=bb.y; acc[i][2]=bb.z; acc[i][3]=bb.w; }

    for (int k4 = 0; k4 < 32; ++k4) {
        float4 w[4], av[4];
        #pragma unroll
        for (int j = 0; j < 4; ++j)
            w[j] = *(const float4*)&Wl[(k4 * 4 + j) * 128 + cg * 4];
        #pragma unroll
        for (int i = 0; i < 4; ++i)
            av[i] = *(const float4*)&As[(rg * 4 + i) * 128 + k4 * 4];
        #pragma unroll
        for (int i = 0; i < 4; ++i) {
            const float a0 = av[i].x, a1 = av[i].y, a2 = av[i].z, a3 = av[i].w;
            acc[i][0] = fmaf(a0, w[0].x, fmaf(a1, w[1].x, fmaf(a2, w[2].x, fmaf(a3, w[3].x, acc[i][0]))));
            acc[i][1] = fmaf(a0, w[0].y, fmaf(a1, w[1].y, fmaf(a2, w[2].y, fmaf(a3, w[3].y, acc[i][1]))));
            acc[i][2] = fmaf(a0, w[0].z, fmaf(a1, w[1].z, fmaf(a2, w[2].z, fmaf(a3, w[3].z, acc[i][2]))));
            acc[i][3] = fmaf(a0, w[0].w, fmaf(a1, w[1].w, fmaf(a2, w[2].w, fmaf(a3, w[3].w, acc[i][3]))));
        }
    }
    #pragma unroll
    for (int i = 0; i < 4; ++i) {
        int row = rowBase + rg * 4 + i;
        if (row < nRows) {
            float4 o; o.x = acc[i][0]; o.y = acc[i][1]; o.z = acc[i][2]; o.w = acc[i][3];
            *(float4*)&Out[(long)row * 128 + cg * 4] = o;
        }
    }
}

// ---- channel-normalize (K=4, dd=32): X -> XN, S ----
__global__ __launch_bounds__(256) void norm_S(
    const float* __restrict__ In, float* __restrict__ NormOut, float* __restrict__ SOut)
{
    int node = blockIdx.x * 4 + (threadIdx.x >> 6);
    if (node >= NN) return;
    int lane = threadIdx.x & 63;             // elems 2*lane, 2*lane+1; 16 lanes = one channel
    float2 v = ((const float2*)(In + (long)node * 128))[lane];
    float ss = red16(v.x * v.x + v.y * v.y);
    float scale = 1.0f / fmaxf(sqrtf(ss), 1e-12f);
    float2 o; o.x = v.x * scale; o.y = v.y * scale;
    ((float2*)(NormOut + (long)node * 128))[lane] = o;
    float t = dpp_add<0xB1>(o.x + o.y);      // pair sum -> s_g
    if (!(lane & 1)) SOut[node * 32 + (lane >> 1)] = t;
}

// ---- node-centric routing: 1 wave/node, 4 edges in flight (16 lanes each) ----
// If SOut: fused channel-normalize epilogue, writes only S (mid iterations).
// If CT:   writes raw c (final iteration of a layer).
__global__ __launch_bounds__(256) void route_nodes(
    const int* __restrict__ rowStart, const int* __restrict__ eSrc,
    float* __restrict__ S, const float* __restrict__ XN,
    float* __restrict__ CT, float* __restrict__ SOut)
{
    int node = blockIdx.x * 4 + (threadIdx.x >> 6);
    if (node >= NN) return;
    int lane = threadIdx.x & 63;
    int slot = lane >> 4;                    // 4 edge slots
    int h = lane & 15;                       // covers elems 2h, 2h+1 of each channel
    float2 s2 = ((const float2*)(S + node * 32))[h];
    float2 a0, a1, a2, a3;
    if (slot == 0) {                         // residual xn[node]
        const float2* xp = (const float2*)(XN + (long)node * 128);
        a0 = xp[h]; a1 = xp[16 + h]; a2 = xp[32 + h]; a3 = xp[48 + h];
    } else {
        a0 = make_float2(0.f, 0.f); a1 = a0; a2 = a0; a3 = a0;
    }
    int beg = rowStart[node], end = rowStart[node + 1];
    for (int i = beg + slot; i < end; i += 4) {
        int src = eSrc[i];
        const float2* zp = (const float2*)(XN + (long)src * 128);
        float2 z0 = zp[h], z1 = zp[16 + h], z2 = zp[32 + h], z3 = zp[48 + h];
        float p0 = red16(z0.x * s2.x + z0.y * s2.y);
        float p1 = red16(z1.x * s2.x + z1.y * s2.y);
        float p2 = red16(z2.x * s2.x + z2.y * s2.y);
        float p3 = red16(z3.x * s2.x + z3.y * s2.y);
        float mx = fmaxf(fmaxf(p0, p1), fmaxf(p2, p3));
        float e0 = __expf(p0 - mx), e1 = __expf(p1 - mx);
        float e2 = __expf(p2 - mx), e3 = __expf(p3 - mx);
        float inv = 1.0f / (e0 + e1 + e2 + e3);
        e0 *= inv; e1 *= inv; e2 *= inv; e3 *= inv;
        a0.x = fmaf(e0, z0.x, a0.x); a0.y = fmaf(e0, z0.y, a0.y);
        a1.x = fmaf(e1, z1.x, a1.x); a1.y = fmaf(e1, z1.y, a1.y);
        a2.x = fmaf(e2, z2.x, a2.x); a2.y = fmaf(e2, z2.y, a2.y);
        a3.x = fmaf(e3, z3.x, a3.x); a3.y = fmaf(e3, z3.y, a3.y);
    }
    // combine the 4 slots (only cross-16 shuffles left on the LDS pipe)
    #pragma unroll
    for (int msk = 16; msk <= 32; msk <<= 1) {
        a0.x += __shfl_xor(a0.x, msk); a0.y += __shfl_xor(a0.y, msk);
        a1.x += __shfl_xor(a1.x, msk); a1.y += __shfl_xor(a1.y, msk);
        a2.x += __shfl_xor(a2.x, msk); a2.y += __shfl_xor(a2.y, msk);
        a3.x += __shfl_xor(a3.x, msk); a3.y += __shfl_xor(a3.y, msk);
    }
    if (SOut) {
        // fused channel-normalize -> only S is needed by the next iteration
        float sc0 = 1.0f / fmaxf(sqrtf(red16(a0.x * a0.x + a0.y * a0.y)), 1e-12f);
        float sc1 = 1.0f / fmaxf(sqrtf(red16(a1.x * a1.x + a1.y * a1.y)), 1e-12f);
        float sc2 = 1.0f / fmaxf(sqrtf(red16(a2.x * a2.x + a2.y * a2.y)), 1e-12f);
        float sc3 = 1.0f / fmaxf(sqrtf(red16(a3.x * a3.x + a3.y * a3.y)), 1e-12f);
        float t0 = dpp_add<0xB1>((a0.x + a0.y) * sc0);
        float t1 = dpp_add<0xB1>((a1.x + a1.y) * sc1);
        float t2 = dpp_add<0xB1>((a2.x + a2.y) * sc2);
        float t3 = dpp_add<0xB1>((a3.x + a3.y) * sc3);
        if (slot == 0 && !(h & 1)) {
            int g = h >> 1;
            SOut[node * 32 +      g] = t0;
            SOut[node * 32 +  8 + g] = t1;
            SOut[node * 32 + 16 + g] = t2;
            SOut[node * 32 + 24 + g] = t3;
        }
    }
    if (CT && slot == 0) {
        float2* cp = (float2*)(CT + (long)node * 128);
        cp[h] = a0; cp[16 + h] = a1; cp[32 + h] = a2; cp[48 + h] = a3;
    }
}

extern "C" void kernel_launch(void* const* d_in, const int* in_sizes, int n_in,
                              void* d_out, int out_size, void* d_ws, size_t ws_size,
                              hipStream_t stream) {
    const void* feat  = d_in[0];
    const void* ei    = d_in[1];
    const void* lin_w = d_in[2];
    const void* lin_b = d_in[3];
    const void* mlp_w = d_in[4];
    const void* mlp_b = d_in[5];
    float* out = (float*)d_out;               // [out(N,128) | x(N,128)] fp32

    const int m = in_sizes[1] / 2;            // 800000 edges

    // ---- workspace layout ----
    char* wsB = (char*)d_ws;
    int*   flags = (int*)wsB;                                  // 256 B slot
    float* Wlin  = (float*)(wsB + 256);                        // 16384
    float* blin  = Wlin + 16384;                               // 128
    float* Wmlp  = blin + 128;                                 // 16384
    float* bmlp  = Wmlp + 16384;                               // 128
    float* S     = bmlp + 128;                                 // NN*32
    float* B0    = S + NN * 32;                                // ND
    float* B1    = B0 + ND;                                    // ND
    float* B2    = B1 + ND;                                    // ND
    int*   srcA  = (int*)(B2 + ND);                            // m
    int*   trgA  = srcA + m;                                   // m
    int*   eSrc  = trgA + m;                                   // m
    int*   deg   = eSrc + m;                                   // NN
    int*   rowStart = deg + NN;                                // NN+1
    int*   cursor   = rowStart + NN + 1;                       // NN
    int*   blkSum   = cursor + NN;                             // 64
    int*   blkOff   = blkSum + 64;                             // 64

    hipMemsetAsync(flags, 0, 8, stream);
    hipMemsetAsync(deg, 0, NN * sizeof(int), stream);
    detect<<<1, 256, 0, stream>>>((const unsigned short*)feat, (const unsigned int*)ei, flags);

    convertN<<<(ND + 255) / 256, 256, 0, stream>>>(feat, B1, ND, flags);
    convertN<<<64, 256, 0, stream>>>(lin_w, Wlin, 16384, flags);
    convertN<<<1, 128, 0, stream>>>(lin_b, blin, 128, flags);
    convertN<<<64, 256, 0, stream>>>(mlp_w, Wmlp, 16384, flags);
    convertN<<<1, 128, 0, stream>>>(mlp_b, bmlp, 128, flags);

    const int edgeBlocks = (m + 255) / 256;
    conv_hist<<<edgeBlocks, 256, 0, stream>>>(ei, srcA, trgA, deg, m, flags);
    scan1<<<SCAN_B, 256, 0, stream>>>(deg, rowStart, blkSum);
    scan2<<<1, 64, 0, stream>>>(blkSum, blkOff, rowStart, m);
    scan3<<<SCAN_B, 256, 0, stream>>>(rowStart, blkOff);
    hipMemcpyAsync(cursor, rowStart, NN * sizeof(int), hipMemcpyDeviceToDevice, stream);
    scatter_csr<<<edgeBlocks, 256, 0, stream>>>(srcA, trgA, cursor, eSrc, m);

    const int gemmBlocks = (NN + 31) / 32;
    const int nodeBlocks = (NN + 3) / 4;

    // x = feat @ lin_w + lin_b   (B1 -> B0)
    gemm128<<<gemmBlocks, 256, 0, stream>>>(B1, Wlin, blin, B0, nullptr, NN);

    // layer 1: X=B0, XN=B1, C=B2
    norm_S<<<nodeBlocks, 256, 0, stream>>>(B0, B1, S);
    route_nodes<<<nodeBlocks, 256, 0, stream>>>(rowStart, eSrc, S, B1, nullptr, S);
    route_nodes<<<nodeBlocks, 256, 0, stream>>>(rowStart, eSrc, S, B1, nullptr, S);
    route_nodes<<<nodeBlocks, 256, 0, stream>>>(rowStart, eSrc, S, B1, B2, nullptr);

    // layer 2: X=B2, XN=B0, C=B1
    norm_S<<<nodeBlocks, 256, 0, stream>>>(B2, B0, S);
    route_nodes<<<nodeBlocks, 256, 0, stream>>>(rowStart, eSrc, S, B0, nullptr, S);
    route_nodes<<<nodeBlocks, 256, 0, stream>>>(rowStart, eSrc, S, B0, nullptr, S);
    route_nodes<<<nodeBlocks, 256, 0, stream>>>(rowStart, eSrc, S, B0, B1, nullptr);

    // out = x @ mlp_w + mlp_b; x write-through fused into staging
    gemm128<<<gemmBlocks, 256, 0, stream>>>(B1, Wmlp, bmlp, out, out + ND, NN);
}

// Round 6
// 609.406 us; speedup vs baseline: 3.9080x; 1.0735x over previous
//
#include <hip/hip_runtime.h>

#define NN 50000
#define ND (NN * 128)
#define SCAN_B 49   // ceil(NN / 1024)

__device__ __forceinline__ float b2f(unsigned short u) {
    union { unsigned int i; float f; } v; v.i = ((unsigned int)u) << 16; return v.f;
}
__device__ __forceinline__ int clampi(int i, int lo, int hi) { return max(lo, min(i, hi)); }

// DPP lane ops (VALU pipe, no LDS traffic)
template<int CTRL>
__device__ __forceinline__ float dmov(float v) {
    return __int_as_float(__builtin_amdgcn_update_dpp(0, __float_as_int(v), CTRL, 0xF, 0xF, true));
}
template<int CTRL> __device__ __forceinline__ float dadd(float v) { return v + dmov<CTRL>(v); }
template<int CTRL> __device__ __forceinline__ float dmax(float v) { return fmaxf(v, dmov<CTRL>(v)); }
// quad all-reduce sum (4 lanes)
__device__ __forceinline__ float qsum(float v) { v = dadd<0xB1>(v); v = dadd<0x4E>(v); return v; }
// row(16) reduce of quad-uniform values
__device__ __forceinline__ float rsum4(float v) { v = dadd<0x124>(v); v = dadd<0x128>(v); return v; }
__device__ __forceinline__ float rmax4(float v) { v = dmax<0x124>(v); v = dmax<0x128>(v); return v; }

// ---- dtype detection: flags[0]=1 if floats fp32; flags[1]=1 if edges int32 ----
__global__ __launch_bounds__(256) void detect(
    const unsigned short* __restrict__ feat_u, const unsigned int* __restrict__ ei_u,
    int* __restrict__ flags)
{
    int tid = threadIdx.x;
    int f32hit = 0;
    for (int i = tid; i < 8192; i += 256) {
        unsigned e = (feat_u[i] >> 7) & 0xFFu;
        if (e >= 0xC0u) f32hit = 1;
    }
    int i32hit = 0;
    for (int i = tid; i < 4096; i += 256)
        if (ei_u[2 * i + 1] != 0u) i32hit = 1;
    if (f32hit) atomicOr(&flags[0], 1);
    if (i32hit) atomicOr(&flags[1], 1);
}

// ---- extract int32 src/trg + degree histogram ----
__global__ __launch_bounds__(256) void conv_hist(
    const void* __restrict__ eiRaw, int* __restrict__ srcA, int* __restrict__ trgA,
    int* __restrict__ deg, int m, const int* __restrict__ flags)
{
    int e = blockIdx.x * 256 + threadIdx.x;
    if (e >= m) return;
    int src, trg;
    if (flags[1]) { const int* p = (const int*)eiRaw; src = p[e]; trg = p[m + e]; }
    else { const long long* p = (const long long*)eiRaw; src = (int)p[e]; trg = (int)p[m + e]; }
    src = clampi(src, 0, NN - 1);
    trg = clampi(trg, 0, NN - 1);
    srcA[e] = src; trgA[e] = trg;
    atomicAdd(&deg[trg], 1);
}

// ---- exclusive scan of deg[NN] -> rowStart[NN+1] ----
__global__ __launch_bounds__(256) void scan1(
    const int* __restrict__ deg, int* __restrict__ rowStart, int* __restrict__ blkSum)
{
    __shared__ int lds[256];
    int blk = blockIdx.x, tid = threadIdx.x;
    int base = blk * 1024 + tid * 4;
    int v[4]; int s = 0;
    #pragma unroll
    for (int j = 0; j < 4; ++j) { int idx = base + j; v[j] = (idx < NN) ? deg[idx] : 0; s += v[j]; }
    lds[tid] = s; __syncthreads();
    for (int off = 1; off < 256; off <<= 1) {
        int x = (tid >= off) ? lds[tid - off] : 0;
        __syncthreads();
        lds[tid] += x;
        __syncthreads();
    }
    int excl = lds[tid] - s;
    if (tid == 255) blkSum[blk] = lds[tid];
    int run = excl;
    #pragma unroll
    for (int j = 0; j < 4; ++j) { int idx = base + j; if (idx < NN) rowStart[idx] = run; run += v[j]; }
}
__global__ __launch_bounds__(64) void scan2(
    int* __restrict__ blkSum, int* __restrict__ blkOff, int* __restrict__ rowStart, int m)
{
    int lane = threadIdx.x;
    int orig = (lane < SCAN_B) ? blkSum[lane] : 0;
    int v = orig;
    for (int off = 1; off < 64; off <<= 1) {
        int x = __shfl_up(v, off);
        if (lane >= off) v += x;
    }
    if (lane < SCAN_B) blkOff[lane] = v - orig;
    if (lane == 0) rowStart[NN] = m;
}
__global__ __launch_bounds__(256) void scan3(int* __restrict__ rowStart, const int* __restrict__ blkOff)
{
    int base = blockIdx.x * 1024 + threadIdx.x * 4;
    int off = blkOff[blockIdx.x];
    #pragma unroll
    for (int j = 0; j < 4; ++j) { int idx = base + j; if (idx < NN) rowStart[idx] += off; }
}

// ---- scatter edges into CSR bins ----
__global__ __launch_bounds__(256) void scatter_csr(
    const int* __restrict__ srcA, const int* __restrict__ trgA,
    int* __restrict__ cursor, int* __restrict__ eSrc, int m)
{
    int e = blockIdx.x * 256 + threadIdx.x;
    if (e >= m) return;
    int pos = atomicAdd(&cursor[trgA[e]], 1);
    eSrc[pos] = srcA[e];
}

// ---- GEMM1: XN = channel_normalize(feat @ W + b), S = s-vector. Reads raw dtypes. ----
__global__ __launch_bounds__(256) void gemm_norm(
    const void* __restrict__ A, const void* __restrict__ W, const void* __restrict__ bias,
    float* __restrict__ XN, float* __restrict__ S, const int* __restrict__ flags)
{
    __shared__ float Wl[128 * 128];   // 64 KB
    __shared__ float As[32 * 128];    // 16 KB
    int tid = threadIdx.x;
    int cg = tid & 31;                // cols 4cg..4cg+3
    int rg = tid >> 5;                // rows rg*4..rg*4+3 (of 32)
    int rowBase = blockIdx.x * 32;
    bool isF32 = flags[0] != 0;

    if (isF32) {
        for (int i = tid * 4; i < 128 * 128; i += 1024)
            *(float4*)&Wl[i] = *(const float4*)&((const float*)W)[i];
    } else {
        for (int i = tid * 4; i < 128 * 128; i += 1024) {
            ushort4 u = *(const ushort4*)&((const unsigned short*)W)[i];
            Wl[i] = b2f(u.x); Wl[i+1] = b2f(u.y); Wl[i+2] = b2f(u.z); Wl[i+3] = b2f(u.w);
        }
    }
    #pragma unroll
    for (int r = 0; r < 4; ++r) {
        int lrow = r * 8 + rg;
        int row = rowBase + lrow;
        float4 v = make_float4(0.f, 0.f, 0.f, 0.f);
        if (row < NN) {
            if (isF32) v = *(const float4*)&((const float*)A)[(long)row * 128 + cg * 4];
            else {
                ushort4 u = *(const ushort4*)&((const unsigned short*)A)[(long)row * 128 + cg * 4];
                v = make_float4(b2f(u.x), b2f(u.y), b2f(u.z), b2f(u.w));
            }
        }
        *(float4*)&As[lrow * 128 + cg * 4] = v;
    }
    float4 bb;
    if (isF32) bb = *(const float4*)&((const float*)bias)[cg * 4];
    else {
        ushort4 u = *(const ushort4*)&((const unsigned short*)bias)[cg * 4];
        bb = make_float4(b2f(u.x), b2f(u.y), b2f(u.z), b2f(u.w));
    }
    __syncthreads();

    float acc[4][4];
    #pragma unroll
    for (int i = 0; i < 4; ++i) { acc[i][0]=bb.x; acc[i][1]=bb.y; acc[i][2]=bb.z; acc[i][3]=bb.w; }

    for (int k4 = 0; k4 < 32; ++k4) {
        float4 w[4], av[4];
        #pragma unroll
        for (int j = 0; j < 4; ++j)
            w[j] = *(const float4*)&Wl[(k4 * 4 + j) * 128 + cg * 4];
        #pragma unroll
        for (int i = 0; i < 4; ++i)
            av[i] = *(const float4*)&As[(rg * 4 + i) * 128 + k4 * 4];
        #pragma unroll
        for (int i = 0; i < 4; ++i) {
            const float a0 = av[i].x, a1 = av[i].y, a2 = av[i].z, a3 = av[i].w;
            acc[i][0] = fmaf(a0, w[0].x, fmaf(a1, w[1].x, fmaf(a2, w[2].x, fmaf(a3, w[3].x, acc[i][0]))));
            acc[i][1] = fmaf(a0, w[0].y, fmaf(a1, w[1].y, fmaf(a2, w[2].y, fmaf(a3, w[3].y, acc[i][1]))));
            acc[i][2] = fmaf(a0, w[0].z, fmaf(a1, w[1].z, fmaf(a2, w[2].z, fmaf(a3, w[3].z, acc[i][2]))));
            acc[i][3] = fmaf(a0, w[0].w, fmaf(a1, w[1].w, fmaf(a2, w[2].w, fmaf(a3, w[3].w, acc[i][3]))));
        }
    }
    // fused channel-normalize epilogue: channel = 8 consecutive cg lanes (32 cols)
    #pragma unroll
    for (int i = 0; i < 4; ++i) {
        int row = rowBase + rg * 4 + i;
        float lss = acc[i][0]*acc[i][0] + acc[i][1]*acc[i][1] + acc[i][2]*acc[i][2] + acc[i][3]*acc[i][3];
        lss += __shfl_xor(lss, 1);
        lss += __shfl_xor(lss, 2);
        lss += __shfl_xor(lss, 4);
        float scale = 1.0f / fmaxf(sqrtf(lss), 1e-12f);
        if (row < NN) {
            float4 o; o.x = acc[i][0]*scale; o.y = acc[i][1]*scale; o.z = acc[i][2]*scale; o.w = acc[i][3]*scale;
            *(float4*)&XN[(long)row * 128 + cg * 4] = o;
            S[row * 32 + cg] = o.x + o.y + o.z + o.w;   // s_a = sum of 4 consecutive normalized elems
        }
    }
}

// ---- GEMM2: Out = A @ W + b (A fp32 from ws); Copy = write-through of A ----
__global__ __launch_bounds__(256) void gemm_copy(
    const float* __restrict__ A, const void* __restrict__ W, const void* __restrict__ bias,
    float* __restrict__ Out, float* __restrict__ Copy, const int* __restrict__ flags)
{
    __shared__ float Wl[128 * 128];
    __shared__ float As[32 * 128];
    int tid = threadIdx.x;
    int cg = tid & 31;
    int rg = tid >> 5;
    int rowBase = blockIdx.x * 32;
    bool isF32 = flags[0] != 0;

    if (isF32) {
        for (int i = tid * 4; i < 128 * 128; i += 1024)
            *(float4*)&Wl[i] = *(const float4*)&((const float*)W)[i];
    } else {
        for (int i = tid * 4; i < 128 * 128; i += 1024) {
            ushort4 u = *(const ushort4*)&((const unsigned short*)W)[i];
            Wl[i] = b2f(u.x); Wl[i+1] = b2f(u.y); Wl[i+2] = b2f(u.z); Wl[i+3] = b2f(u.w);
        }
    }
    #pragma unroll
    for (int r = 0; r < 4; ++r) {
        int lrow = r * 8 + rg;
        int row = rowBase + lrow;
        float4 v = make_float4(0.f, 0.f, 0.f, 0.f);
        if (row < NN) v = *(const float4*)&A[(long)row * 128 + cg * 4];
        *(float4*)&As[lrow * 128 + cg * 4] = v;
        if (row < NN) *(float4*)&Copy[(long)row * 128 + cg * 4] = v;
    }
    float4 bb;
    if (isF32) bb = *(const float4*)&((const float*)bias)[cg * 4];
    else {
        ushort4 u = *(const ushort4*)&((const unsigned short*)bias)[cg * 4];
        bb = make_float4(b2f(u.x), b2f(u.y), b2f(u.z), b2f(u.w));
    }
    __syncthreads();

    float acc[4][4];
    #pragma unroll
    for (int i = 0; i < 4; ++i) { acc[i][0]=bb.x; acc[i][1]=bb.y; acc[i][2]=bb.z; acc[i][3]=bb.w; }

    for (int k4 = 0; k4 < 32; ++k4) {
        float4 w[4], av[4];
        #pragma unroll
        for (int j = 0; j < 4; ++j)
            w[j] = *(const float4*)&Wl[(k4 * 4 + j) * 128 + cg * 4];
        #pragma unroll
        for (int i = 0; i < 4; ++i)
            av[i] = *(const float4*)&As[(rg * 4 + i) * 128 + k4 * 4];
        #pragma unroll
        for (int i = 0; i < 4; ++i) {
            const float a0 = av[i].x, a1 = av[i].y, a2 = av[i].z, a3 = av[i].w;
            acc[i][0] = fmaf(a0, w[0].x, fmaf(a1, w[1].x, fmaf(a2, w[2].x, fmaf(a3, w[3].x, acc[i][0]))));
            acc[i][1] = fmaf(a0, w[0].y, fmaf(a1, w[1].y, fmaf(a2, w[2].y, fmaf(a3, w[3].y, acc[i][1]))));
            acc[i][2] = fmaf(a0, w[0].z, fmaf(a1, w[1].z, fmaf(a2, w[2].z, fmaf(a3, w[3].z, acc[i][2]))));
            acc[i][3] = fmaf(a0, w[0].w, fmaf(a1, w[1].w, fmaf(a2, w[2].w, fmaf(a3, w[3].w, acc[i][3]))));
        }
    }
    #pragma unroll
    for (int i = 0; i < 4; ++i) {
        int row = rowBase + rg * 4 + i;
        if (row < NN) {
            float4 o; o.x = acc[i][0]; o.y = acc[i][1]; o.z = acc[i][2]; o.w = acc[i][3];
            *(float4*)&Out[(long)row * 128 + cg * 4] = o;
        }
    }
}

// ---- node-centric routing: 1 wave/node, 4 slots x 16 lanes; lane holds 8 elems ----
// Epilogue modes: SOut!=0 -> channel-normalize, write S (+XNOut if given); CT!=0 -> raw c.
__global__ __launch_bounds__(256) void route_nodes(
    const int* __restrict__ rowStart, const int* __restrict__ eSrc,
    const float* __restrict__ S, const float* __restrict__ XN,
    float* __restrict__ CT, float* __restrict__ SOut, float* __restrict__ XNOut)
{
    int node = blockIdx.x * 4 + (threadIdx.x >> 6);
    if (node >= NN) return;
    int lane = threadIdx.x & 63;
    int slot = lane >> 4;                    // 4 edge slots (DPP rows)
    int h = lane & 15;                       // elems 8h..8h+7, channel h>>2
    const float4* sp = (const float4*)(S + node * 32 + 8 * (h & 3));
    float4 sA = sp[0], sB = sp[1];
    float4 aA = make_float4(0.f,0.f,0.f,0.f), aB = aA;
    if (slot == 0) {                         // residual xn[node]
        const float4* xp = (const float4*)(XN + (long)node * 128 + 8 * h);
        aA = xp[0]; aB = xp[1];
    }
    int beg = rowStart[node], end = rowStart[node + 1];
    int nIter = (end - beg + 3) >> 2;
    if (nIter > 0) {
        int i0 = beg + slot;
        int hi = end - 1;
        const char* XNb = (const char*)XN;
        long loff = (long)8 * h * 4;
        int src_cur  = eSrc[clampi(i0, 0, hi)];
        int src_next = eSrc[clampi(i0 + 4, 0, hi)];
        float4 zA = *(const float4*)(XNb + ((long)src_cur * 512 + loff));
        float4 zB = *(const float4*)(XNb + ((long)src_cur * 512 + loff + 16));
        for (int t = 0; t < nIter; ++t) {
            // prefetch: row for t+1 (index already resident), index for t+2
            float4 zAn = *(const float4*)(XNb + ((long)src_next * 512 + loff));
            float4 zBn = *(const float4*)(XNb + ((long)src_next * 512 + loff + 16));
            int src_nn = eSrc[clampi(i0 + (t + 2) * 4, 0, hi)];
            // p_k = <z_k, s>: 8-elem partial then quad sum
            float p = fmaf(zA.x, sA.x, fmaf(zA.y, sA.y, fmaf(zA.z, sA.z, fmaf(zA.w, sA.w,
                      fmaf(zB.x, sB.x, fmaf(zB.y, sB.y, fmaf(zB.z, sB.z, zB.w * sB.w)))))));
            p = qsum(p);                     // p_k broadcast within quad (channel)
            float mx = rmax4(p);             // max over 4 channels (row of 16)
            float ex = __expf(p - mx);
            float sm = rsum4(ex);            // sum over 4 channels
            float w = ex * __builtin_amdgcn_rcpf(sm);
            bool valid = (i0 + t * 4) < end;
            w = valid ? w : 0.f;
            aA.x = fmaf(w, zA.x, aA.x); aA.y = fmaf(w, zA.y, aA.y);
            aA.z = fmaf(w, zA.z, aA.z); aA.w = fmaf(w, zA.w, aA.w);
            aB.x = fmaf(w, zB.x, aB.x); aB.y = fmaf(w, zB.y, aB.y);
            aB.z = fmaf(w, zB.z, aB.z); aB.w = fmaf(w, zB.w, aB.w);
            zA = zAn; zB = zBn; src_next = src_nn;
        }
    }
    // combine 4 slots
    aA.x += __shfl_xor(aA.x, 16); aA.x += __shfl_xor(aA.x, 32);
    aA.y += __shfl_xor(aA.y, 16); aA.y += __shfl_xor(aA.y, 32);
    aA.z += __shfl_xor(aA.z, 16); aA.z += __shfl_xor(aA.z, 32);
    aA.w += __shfl_xor(aA.w, 16); aA.w += __shfl_xor(aA.w, 32);
    aB.x += __shfl_xor(aB.x, 16); aB.x += __shfl_xor(aB.x, 32);
    aB.y += __shfl_xor(aB.y, 16); aB.y += __shfl_xor(aB.y, 32);
    aB.z += __shfl_xor(aB.z, 16); aB.z += __shfl_xor(aB.z, 32);
    aB.w += __shfl_xor(aB.w, 16); aB.w += __shfl_xor(aB.w, 32);

    if (SOut) {
        // channel-normalize: channel = quad (4 lanes x 8 elems = 32)
        float ssq = aA.x*aA.x + aA.y*aA.y + aA.z*aA.z + aA.w*aA.w
                  + aB.x*aB.x + aB.y*aB.y + aB.z*aB.z + aB.w*aB.w;
        ssq = qsum(ssq);
        float scale = 1.0f / fmaxf(sqrtf(ssq), 1e-12f);
        if (slot == 0) {
            if (XNOut) {
                float4 o0; o0.x=aA.x*scale; o0.y=aA.y*scale; o0.z=aA.z*scale; o0.w=aA.w*scale;
                float4 o1; o1.x=aB.x*scale; o1.y=aB.y*scale; o1.z=aB.z*scale; o1.w=aB.w*scale;
                float4* xo = (float4*)(XNOut + (long)node * 128 + 8 * h);
                xo[0] = o0; xo[1] = o1;
            }
            float2 t;
            t.x = (aA.x + aA.y + aA.z + aA.w) * scale;
            t.y = (aB.x + aB.y + aB.z + aB.w) * scale;
            *(float2*)(SOut + node * 32 + 2 * h) = t;
        }
    }
    if (CT && slot == 0) {
        float4* cp = (float4*)(CT + (long)node * 128 + 8 * h);
        cp[0] = aA; cp[1] = aB;
    }
}

extern "C" void kernel_launch(void* const* d_in, const int* in_sizes, int n_in,
                              void* d_out, int out_size, void* d_ws, size_t ws_size,
                              hipStream_t stream) {
    const void* feat  = d_in[0];
    const void* ei    = d_in[1];
    const void* lin_w = d_in[2];
    const void* lin_b = d_in[3];
    const void* mlp_w = d_in[4];
    const void* mlp_b = d_in[5];
    float* out = (float*)d_out;               // [out(N,128) | x(N,128)] fp32

    const int m = in_sizes[1] / 2;            // 800000 edges

    // ---- workspace layout ----
    char* wsB = (char*)d_ws;
    int*   flags = (int*)wsB;                                  // 256 B slot
    float* S     = (float*)(wsB + 256);                        // NN*32
    float* B0    = S + NN * 32;                                // ND
    float* B1    = B0 + ND;                                    // ND
    float* B2    = B1 + ND;                                    // ND
    int*   srcA  = (int*)(B2 + ND);                            // m
    int*   trgA  = srcA + m;                                   // m
    int*   eSrc  = trgA + m;                                   // m
    int*   deg   = eSrc + m;                                   // NN
    int*   rowStart = deg + NN;                                // NN+1
    int*   cursor   = rowStart + NN + 1;                       // NN
    int*   blkSum   = cursor + NN;                             // 64
    int*   blkOff   = blkSum + 64;                             // 64

    hipMemsetAsync(flags, 0, 8, stream);
    hipMemsetAsync(deg, 0, NN * sizeof(int), stream);
    detect<<<1, 256, 0, stream>>>((const unsigned short*)feat, (const unsigned int*)ei, flags);

    const int edgeBlocks = (m + 255) / 256;
    conv_hist<<<edgeBlocks, 256, 0, stream>>>(ei, srcA, trgA, deg, m, flags);
    scan1<<<SCAN_B, 256, 0, stream>>>(deg, rowStart, blkSum);
    scan2<<<1, 64, 0, stream>>>(blkSum, blkOff, rowStart, m);
    scan3<<<SCAN_B, 256, 0, stream>>>(rowStart, blkOff);
    hipMemcpyAsync(cursor, rowStart, NN * sizeof(int), hipMemcpyDeviceToDevice, stream);
    scatter_csr<<<edgeBlocks, 256, 0, stream>>>(srcA, trgA, cursor, eSrc, m);

    const int gemmBlocks = (NN + 31) / 32;
    const int nodeBlocks = (NN + 3) / 4;

    // gemm1 + fused normalize: feat -> XN(B1), S
    gemm_norm<<<gemmBlocks, 256, 0, stream>>>(feat, lin_w, lin_b, B1, S, flags);

    // layer 1 (XN=B1): two S-only iterations, final writes normalized XN2(B0)+S
    route_nodes<<<nodeBlocks, 256, 0, stream>>>(rowStart, eSrc, S, B1, nullptr, S, nullptr);
    route_nodes<<<nodeBlocks, 256, 0, stream>>>(rowStart, eSrc, S, B1, nullptr, S, nullptr);
    route_nodes<<<nodeBlocks, 256, 0, stream>>>(rowStart, eSrc, S, B1, nullptr, S, B0);

    // layer 2 (XN=B0): two S-only iterations, final writes raw x (B2)
    route_nodes<<<nodeBlocks, 256, 0, stream>>>(rowStart, eSrc, S, B0, nullptr, S, nullptr);
    route_nodes<<<nodeBlocks, 256, 0, stream>>>(rowStart, eSrc, S, B0, nullptr, S, nullptr);
    route_nodes<<<nodeBlocks, 256, 0, stream>>>(rowStart, eSrc, S, B0, B2, nullptr, nullptr);

    // out = x @ mlp_w + mlp_b; x copied to out+ND during staging
    gemm_copy<<<gemmBlocks, 256, 0, stream>>>(B2, mlp_w, mlp_b, out, out + ND, flags);
}

// Round 7
// 496.839 us; speedup vs baseline: 4.7934x; 1.2266x over previous
//
#include <hip/hip_runtime.h>

#define NN 50000
#define ND (NN * 128)
#define SCAN_B 49   // ceil(NN / 1024)

__device__ __forceinline__ float b2f(unsigned short u) {
    union { unsigned int i; float f; } v; v.i = ((unsigned int)u) << 16; return v.f;
}
__device__ __forceinline__ unsigned short f2b(float f) {      // RNE bf16 pack
    union { float f; unsigned int i; } v; v.f = f;
    return (unsigned short)((v.i + 0x7fffu + ((v.i >> 16) & 1u)) >> 16);
}
__device__ __forceinline__ unsigned int pack2(float lo, float hi) {
    return (unsigned int)f2b(lo) | ((unsigned int)f2b(hi) << 16);
}
__device__ __forceinline__ float unlo(unsigned int u) { return __uint_as_float(u << 16); }
__device__ __forceinline__ float unhi(unsigned int u) { return __uint_as_float(u & 0xFFFF0000u); }
__device__ __forceinline__ int clampi(int i, int lo, int hi) { return max(lo, min(i, hi)); }

// DPP lane ops (VALU pipe, no LDS traffic)
template<int CTRL>
__device__ __forceinline__ float dmov(float v) {
    return __int_as_float(__builtin_amdgcn_update_dpp(0, __float_as_int(v), CTRL, 0xF, 0xF, true));
}
template<int CTRL> __device__ __forceinline__ float dadd(float v) { return v + dmov<CTRL>(v); }
template<int CTRL> __device__ __forceinline__ float dmax(float v) { return fmaxf(v, dmov<CTRL>(v)); }
__device__ __forceinline__ float qsum(float v) { v = dadd<0xB1>(v); v = dadd<0x4E>(v); return v; }
__device__ __forceinline__ float rsum4(float v) { v = dadd<0x124>(v); v = dadd<0x128>(v); return v; }
__device__ __forceinline__ float rmax4(float v) { v = dmax<0x124>(v); v = dmax<0x128>(v); return v; }

// ---- dtype detection: flags[0]=1 if floats fp32; flags[1]=1 if edges int32 ----
__global__ __launch_bounds__(256) void detect(
    const unsigned short* __restrict__ feat_u, const unsigned int* __restrict__ ei_u,
    int* __restrict__ flags)
{
    int tid = threadIdx.x;
    int f32hit = 0;
    for (int i = tid; i < 8192; i += 256) {
        unsigned e = (feat_u[i] >> 7) & 0xFFu;
        if (e >= 0xC0u) f32hit = 1;
    }
    int i32hit = 0;
    for (int i = tid; i < 4096; i += 256)
        if (ei_u[2 * i + 1] != 0u) i32hit = 1;
    if (f32hit) atomicOr(&flags[0], 1);
    if (i32hit) atomicOr(&flags[1], 1);
}

// ---- extract int32 src/trg + degree histogram ----
__global__ __launch_bounds__(256) void conv_hist(
    const void* __restrict__ eiRaw, int* __restrict__ srcA, int* __restrict__ trgA,
    int* __restrict__ deg, int m, const int* __restrict__ flags)
{
    int e = blockIdx.x * 256 + threadIdx.x;
    if (e >= m) return;
    int src, trg;
    if (flags[1]) { const int* p = (const int*)eiRaw; src = p[e]; trg = p[m + e]; }
    else { const long long* p = (const long long*)eiRaw; src = (int)p[e]; trg = (int)p[m + e]; }
    src = clampi(src, 0, NN - 1);
    trg = clampi(trg, 0, NN - 1);
    srcA[e] = src; trgA[e] = trg;
    atomicAdd(&deg[trg], 1);
}

// ---- exclusive scan of deg[NN] -> rowStart[NN+1] ----
__global__ __launch_bounds__(256) void scan1(
    const int* __restrict__ deg, int* __restrict__ rowStart, int* __restrict__ blkSum)
{
    __shared__ int lds[256];
    int blk = blockIdx.x, tid = threadIdx.x;
    int base = blk * 1024 + tid * 4;
    int v[4]; int s = 0;
    #pragma unroll
    for (int j = 0; j < 4; ++j) { int idx = base + j; v[j] = (idx < NN) ? deg[idx] : 0; s += v[j]; }
    lds[tid] = s; __syncthreads();
    for (int off = 1; off < 256; off <<= 1) {
        int x = (tid >= off) ? lds[tid - off] : 0;
        __syncthreads();
        lds[tid] += x;
        __syncthreads();
    }
    int excl = lds[tid] - s;
    if (tid == 255) blkSum[blk] = lds[tid];
    int run = excl;
    #pragma unroll
    for (int j = 0; j < 4; ++j) { int idx = base + j; if (idx < NN) rowStart[idx] = run; run += v[j]; }
}
__global__ __launch_bounds__(64) void scan2(
    int* __restrict__ blkSum, int* __restrict__ blkOff, int* __restrict__ rowStart, int m)
{
    int lane = threadIdx.x;
    int orig = (lane < SCAN_B) ? blkSum[lane] : 0;
    int v = orig;
    for (int off = 1; off < 64; off <<= 1) {
        int x = __shfl_up(v, off);
        if (lane >= off) v += x;
    }
    if (lane < SCAN_B) blkOff[lane] = v - orig;
    if (lane == 0) rowStart[NN] = m;
}
__global__ __launch_bounds__(256) void scan3(int* __restrict__ rowStart, const int* __restrict__ blkOff)
{
    int base = blockIdx.x * 1024 + threadIdx.x * 4;
    int off = blkOff[blockIdx.x];
    #pragma unroll
    for (int j = 0; j < 4; ++j) { int idx = base + j; if (idx < NN) rowStart[idx] += off; }
}

// ---- scatter edges into CSR bins ----
__global__ __launch_bounds__(256) void scatter_csr(
    const int* __restrict__ srcA, const int* __restrict__ trgA,
    int* __restrict__ cursor, int* __restrict__ eSrc, int m)
{
    int e = blockIdx.x * 256 + threadIdx.x;
    if (e >= m) return;
    int pos = atomicAdd(&cursor[trgA[e]], 1);
    eSrc[pos] = srcA[e];
}

// ---- GEMM1: XNh(bf16) = channel_normalize(feat @ W + b), S(fp32). Raw dtypes in. ----
__global__ __launch_bounds__(256) void gemm_norm(
    const void* __restrict__ A, const void* __restrict__ W, const void* __restrict__ bias,
    unsigned short* __restrict__ XNh, float* __restrict__ S, const int* __restrict__ flags)
{
    __shared__ float Wl[128 * 128];
    __shared__ float As[32 * 128];
    int tid = threadIdx.x;
    int cg = tid & 31;                // cols 4cg..4cg+3
    int rg = tid >> 5;                // rows rg*4..rg*4+3 (of 32)
    int rowBase = blockIdx.x * 32;
    bool isF32 = flags[0] != 0;

    if (isF32) {
        for (int i = tid * 4; i < 128 * 128; i += 1024)
            *(float4*)&Wl[i] = *(const float4*)&((const float*)W)[i];
    } else {
        for (int i = tid * 4; i < 128 * 128; i += 1024) {
            ushort4 u = *(const ushort4*)&((const unsigned short*)W)[i];
            Wl[i] = b2f(u.x); Wl[i+1] = b2f(u.y); Wl[i+2] = b2f(u.z); Wl[i+3] = b2f(u.w);
        }
    }
    #pragma unroll
    for (int r = 0; r < 4; ++r) {
        int lrow = r * 8 + rg;
        int row = rowBase + lrow;
        float4 v = make_float4(0.f, 0.f, 0.f, 0.f);
        if (row < NN) {
            if (isF32) v = *(const float4*)&((const float*)A)[(long)row * 128 + cg * 4];
            else {
                ushort4 u = *(const ushort4*)&((const unsigned short*)A)[(long)row * 128 + cg * 4];
                v = make_float4(b2f(u.x), b2f(u.y), b2f(u.z), b2f(u.w));
            }
        }
        *(float4*)&As[lrow * 128 + cg * 4] = v;
    }
    float4 bb;
    if (isF32) bb = *(const float4*)&((const float*)bias)[cg * 4];
    else {
        ushort4 u = *(const ushort4*)&((const unsigned short*)bias)[cg * 4];
        bb = make_float4(b2f(u.x), b2f(u.y), b2f(u.z), b2f(u.w));
    }
    __syncthreads();

    float acc[4][4];
    #pragma unroll
    for (int i = 0; i < 4; ++i) { acc[i][0]=bb.x; acc[i][1]=bb.y; acc[i][2]=bb.z; acc[i][3]=bb.w; }

    for (int k4 = 0; k4 < 32; ++k4) {
        float4 w[4], av[4];
        #pragma unroll
        for (int j = 0; j < 4; ++j)
            w[j] = *(const float4*)&Wl[(k4 * 4 + j) * 128 + cg * 4];
        #pragma unroll
        for (int i = 0; i < 4; ++i)
            av[i] = *(const float4*)&As[(rg * 4 + i) * 128 + k4 * 4];
        #pragma unroll
        for (int i = 0; i < 4; ++i) {
            const float a0 = av[i].x, a1 = av[i].y, a2 = av[i].z, a3 = av[i].w;
            acc[i][0] = fmaf(a0, w[0].x, fmaf(a1, w[1].x, fmaf(a2, w[2].x, fmaf(a3, w[3].x, acc[i][0]))));
            acc[i][1] = fmaf(a0, w[0].y, fmaf(a1, w[1].y, fmaf(a2, w[2].y, fmaf(a3, w[3].y, acc[i][1]))));
            acc[i][2] = fmaf(a0, w[0].z, fmaf(a1, w[1].z, fmaf(a2, w[2].z, fmaf(a3, w[3].z, acc[i][2]))));
            acc[i][3] = fmaf(a0, w[0].w, fmaf(a1, w[1].w, fmaf(a2, w[2].w, fmaf(a3, w[3].w, acc[i][3]))));
        }
    }
    #pragma unroll
    for (int i = 0; i < 4; ++i) {
        int row = rowBase + rg * 4 + i;
        float lss = acc[i][0]*acc[i][0] + acc[i][1]*acc[i][1] + acc[i][2]*acc[i][2] + acc[i][3]*acc[i][3];
        lss += __shfl_xor(lss, 1);
        lss += __shfl_xor(lss, 2);
        lss += __shfl_xor(lss, 4);
        float scale = 1.0f / fmaxf(sqrtf(lss), 1e-12f);
        if (row < NN) {
            float4 o; o.x = acc[i][0]*scale; o.y = acc[i][1]*scale; o.z = acc[i][2]*scale; o.w = acc[i][3]*scale;
            uint2 pk; pk.x = pack2(o.x, o.y); pk.y = pack2(o.z, o.w);
            *(uint2*)((char*)XNh + (long)row * 256 + cg * 8) = pk;
            S[row * 32 + cg] = o.x + o.y + o.z + o.w;
        }
    }
}

// ---- GEMM2: Out = A @ W + b (A fp32) ----
__global__ __launch_bounds__(256) void gemm_plain(
    const float* __restrict__ A, const void* __restrict__ W, const void* __restrict__ bias,
    float* __restrict__ Out, const int* __restrict__ flags)
{
    __shared__ float Wl[128 * 128];
    __shared__ float As[32 * 128];
    int tid = threadIdx.x;
    int cg = tid & 31;
    int rg = tid >> 5;
    int rowBase = blockIdx.x * 32;
    bool isF32 = flags[0] != 0;

    if (isF32) {
        for (int i = tid * 4; i < 128 * 128; i += 1024)
            *(float4*)&Wl[i] = *(const float4*)&((const float*)W)[i];
    } else {
        for (int i = tid * 4; i < 128 * 128; i += 1024) {
            ushort4 u = *(const ushort4*)&((const unsigned short*)W)[i];
            Wl[i] = b2f(u.x); Wl[i+1] = b2f(u.y); Wl[i+2] = b2f(u.z); Wl[i+3] = b2f(u.w);
        }
    }
    #pragma unroll
    for (int r = 0; r < 4; ++r) {
        int lrow = r * 8 + rg;
        int row = rowBase + lrow;
        float4 v = make_float4(0.f, 0.f, 0.f, 0.f);
        if (row < NN) v = *(const float4*)&A[(long)row * 128 + cg * 4];
        *(float4*)&As[lrow * 128 + cg * 4] = v;
    }
    float4 bb;
    if (isF32) bb = *(const float4*)&((const float*)bias)[cg * 4];
    else {
        ushort4 u = *(const ushort4*)&((const unsigned short*)bias)[cg * 4];
        bb = make_float4(b2f(u.x), b2f(u.y), b2f(u.z), b2f(u.w));
    }
    __syncthreads();

    float acc[4][4];
    #pragma unroll
    for (int i = 0; i < 4; ++i) { acc[i][0]=bb.x; acc[i][1]=bb.y; acc[i][2]=bb.z; acc[i][3]=bb.w; }

    for (int k4 = 0; k4 < 32; ++k4) {
        float4 w[4], av[4];
        #pragma unroll
        for (int j = 0; j < 4; ++j)
            w[j] = *(const float4*)&Wl[(k4 * 4 + j) * 128 + cg * 4];
        #pragma unroll
        for (int i = 0; i < 4; ++i)
            av[i] = *(const float4*)&As[(rg * 4 + i) * 128 + k4 * 4];
        #pragma unroll
        for (int i = 0; i < 4; ++i) {
            const float a0 = av[i].x, a1 = av[i].y, a2 = av[i].z, a3 = av[i].w;
            acc[i][0] = fmaf(a0, w[0].x, fmaf(a1, w[1].x, fmaf(a2, w[2].x, fmaf(a3, w[3].x, acc[i][0]))));
            acc[i][1] = fmaf(a0, w[0].y, fmaf(a1, w[1].y, fmaf(a2, w[2].y, fmaf(a3, w[3].y, acc[i][1]))));
            acc[i][2] = fmaf(a0, w[0].z, fmaf(a1, w[1].z, fmaf(a2, w[2].z, fmaf(a3, w[3].z, acc[i][2]))));
            acc[i][3] = fmaf(a0, w[0].w, fmaf(a1, w[1].w, fmaf(a2, w[2].w, fmaf(a3, w[3].w, acc[i][3]))));
        }
    }
    #pragma unroll
    for (int i = 0; i < 4; ++i) {
        int row = rowBase + rg * 4 + i;
        if (row < NN) {
            float4 o; o.x = acc[i][0]; o.y = acc[i][1]; o.z = acc[i][2]; o.w = acc[i][3];
            *(float4*)&Out[(long)row * 128 + cg * 4] = o;
        }
    }
}

// ---- node-centric routing over bf16 XN: 1 wave/node, 4 slots x 16 lanes x 8 elems ----
// Epilogues: SOut -> channel-normalize, write fp32 S (+bf16 XNOut); CT -> raw fp32 c.
__global__ __launch_bounds__(256) void route_nodes(
    const int* __restrict__ rowStart, const int* __restrict__ eSrc,
    const float* __restrict__ S, const unsigned short* __restrict__ XNh,
    float* __restrict__ CT, float* __restrict__ SOut, unsigned short* __restrict__ XNOut)
{
    int node = blockIdx.x * 4 + (threadIdx.x >> 6);
    if (node >= NN) return;
    int lane = threadIdx.x & 63;
    int slot = lane >> 4;                    // 4 edge slots
    int h = lane & 15;                       // elems 8h..8h+7, channel h>>2
    const float4* sp = (const float4*)(S + node * 32 + 8 * (h & 3));
    float4 sA = sp[0], sB = sp[1];
    float4 aA = make_float4(0.f,0.f,0.f,0.f), aB = aA;
    const char* XNb = (const char*)XNh;
    long loff = (long)(h << 4);
    if (slot == 0) {                         // residual xn[node] (bf16)
        uint4 r = *(const uint4*)(XNb + (long)node * 256 + loff);
        aA.x = unlo(r.x); aA.y = unhi(r.x); aA.z = unlo(r.y); aA.w = unhi(r.y);
        aB.x = unlo(r.z); aB.y = unhi(r.z); aB.z = unlo(r.w); aB.w = unhi(r.w);
    }
    int beg = rowStart[node], end = rowStart[node + 1];
    int nIter = (end - beg + 3) >> 2;
    if (nIter > 0) {
        int i0 = beg + slot;
        int hi = end - 1;
        int src_cur  = eSrc[clampi(i0, 0, hi)];
        int src_next = eSrc[clampi(i0 + 4, 0, hi)];
        uint4 zu = *(const uint4*)(XNb + ((long)src_cur * 256 + loff));
        for (int t = 0; t < nIter; ++t) {
            uint4 zun = *(const uint4*)(XNb + ((long)src_next * 256 + loff));
            int src_nn = eSrc[clampi(i0 + (t + 2) * 4, 0, hi)];
            float z0 = unlo(zu.x), z1 = unhi(zu.x), z2 = unlo(zu.y), z3 = unhi(zu.y);
            float z4 = unlo(zu.z), z5 = unhi(zu.z), z6 = unlo(zu.w), z7 = unhi(zu.w);
            float p = fmaf(z0, sA.x, fmaf(z1, sA.y, fmaf(z2, sA.z, fmaf(z3, sA.w,
                      fmaf(z4, sB.x, fmaf(z5, sB.y, fmaf(z6, sB.z, z7 * sB.w)))))));
            p = qsum(p);                     // p_k within quad (channel)
            float mx = rmax4(p);             // softmax across 4 channels
            float ex = __expf(p - mx);
            float sm = rsum4(ex);
            float w = ex * __builtin_amdgcn_rcpf(sm);
            w = ((i0 + t * 4) < end) ? w : 0.f;
            aA.x = fmaf(w, z0, aA.x); aA.y = fmaf(w, z1, aA.y);
            aA.z = fmaf(w, z2, aA.z); aA.w = fmaf(w, z3, aA.w);
            aB.x = fmaf(w, z4, aB.x); aB.y = fmaf(w, z5, aB.y);
            aB.z = fmaf(w, z6, aB.z); aB.w = fmaf(w, z7, aB.w);
            zu = zun; src_next = src_nn;
        }
    }
    // combine 4 slots
    aA.x += __shfl_xor(aA.x, 16); aA.x += __shfl_xor(aA.x, 32);
    aA.y += __shfl_xor(aA.y, 16); aA.y += __shfl_xor(aA.y, 32);
    aA.z += __shfl_xor(aA.z, 16); aA.z += __shfl_xor(aA.z, 32);
    aA.w += __shfl_xor(aA.w, 16); aA.w += __shfl_xor(aA.w, 32);
    aB.x += __shfl_xor(aB.x, 16); aB.x += __shfl_xor(aB.x, 32);
    aB.y += __shfl_xor(aB.y, 16); aB.y += __shfl_xor(aB.y, 32);
    aB.z += __shfl_xor(aB.z, 16); aB.z += __shfl_xor(aB.z, 32);
    aB.w += __shfl_xor(aB.w, 16); aB.w += __shfl_xor(aB.w, 32);

    if (SOut) {
        float ssq = aA.x*aA.x + aA.y*aA.y + aA.z*aA.z + aA.w*aA.w
                  + aB.x*aB.x + aB.y*aB.y + aB.z*aB.z + aB.w*aB.w;
        ssq = qsum(ssq);
        float scale = 1.0f / fmaxf(sqrtf(ssq), 1e-12f);
        if (slot == 0) {
            float4 o0; o0.x=aA.x*scale; o0.y=aA.y*scale; o0.z=aA.z*scale; o0.w=aA.w*scale;
            float4 o1; o1.x=aB.x*scale; o1.y=aB.y*scale; o1.z=aB.z*scale; o1.w=aB.w*scale;
            if (XNOut) {
                uint4 pk;
                pk.x = pack2(o0.x, o0.y); pk.y = pack2(o0.z, o0.w);
                pk.z = pack2(o1.x, o1.y); pk.w = pack2(o1.z, o1.w);
                *(uint4*)((char*)XNOut + (long)node * 256 + loff) = pk;
            }
            float2 t;
            t.x = o0.x + o0.y + o0.z + o0.w;
            t.y = o1.x + o1.y + o1.z + o1.w;
            *(float2*)(SOut + node * 32 + 2 * h) = t;
        }
    }
    if (CT && slot == 0) {
        float4* cp = (float4*)(CT + (long)node * 128 + 8 * h);
        cp[0] = aA; cp[1] = aB;
    }
}

extern "C" void kernel_launch(void* const* d_in, const int* in_sizes, int n_in,
                              void* d_out, int out_size, void* d_ws, size_t ws_size,
                              hipStream_t stream) {
    const void* feat  = d_in[0];
    const void* ei    = d_in[1];
    const void* lin_w = d_in[2];
    const void* lin_b = d_in[3];
    const void* mlp_w = d_in[4];
    const void* mlp_b = d_in[5];
    float* out = (float*)d_out;               // [out(N,128) | x(N,128)] fp32

    const int m = in_sizes[1] / 2;            // 800000 edges

    // ---- workspace layout ----
    char* wsB = (char*)d_ws;
    int*   flags = (int*)wsB;                                  // 256 B slot
    float* S     = (float*)(wsB + 256);                        // NN*32 fp32
    unsigned short* XH1 = (unsigned short*)(S + NN * 32);      // NN*128 bf16
    unsigned short* XH2 = XH1 + ND;                            // NN*128 bf16
    int*   srcA  = (int*)(XH2 + ND);                           // m
    int*   trgA  = srcA + m;                                   // m
    int*   eSrc  = trgA + m;                                   // m
    int*   deg   = eSrc + m;                                   // NN
    int*   rowStart = deg + NN;                                // NN+1
    int*   cursor   = rowStart + NN + 1;                       // NN
    int*   blkSum   = cursor + NN;                             // 64
    int*   blkOff   = blkSum + 64;                             // 64

    hipMemsetAsync(flags, 0, 8, stream);
    hipMemsetAsync(deg, 0, NN * sizeof(int), stream);
    detect<<<1, 256, 0, stream>>>((const unsigned short*)feat, (const unsigned int*)ei, flags);

    const int edgeBlocks = (m + 255) / 256;
    conv_hist<<<edgeBlocks, 256, 0, stream>>>(ei, srcA, trgA, deg, m, flags);
    scan1<<<SCAN_B, 256, 0, stream>>>(deg, rowStart, blkSum);
    scan2<<<1, 64, 0, stream>>>(blkSum, blkOff, rowStart, m);
    scan3<<<SCAN_B, 256, 0, stream>>>(rowStart, blkOff);
    hipMemcpyAsync(cursor, rowStart, NN * sizeof(int), hipMemcpyDeviceToDevice, stream);
    scatter_csr<<<edgeBlocks, 256, 0, stream>>>(srcA, trgA, cursor, eSrc, m);

    const int gemmBlocks = (NN + 31) / 32;
    const int nodeBlocks = (NN + 3) / 4;

    // gemm1 + fused normalize: feat -> XH1 (bf16), S
    gemm_norm<<<gemmBlocks, 256, 0, stream>>>(feat, lin_w, lin_b, XH1, S, flags);

    // layer 1 (XN=XH1): two S-only iterations, final writes bf16 XH2 + S
    route_nodes<<<nodeBlocks, 256, 0, stream>>>(rowStart, eSrc, S, XH1, nullptr, S, nullptr);
    route_nodes<<<nodeBlocks, 256, 0, stream>>>(rowStart, eSrc, S, XH1, nullptr, S, nullptr);
    route_nodes<<<nodeBlocks, 256, 0, stream>>>(rowStart, eSrc, S, XH1, nullptr, S, XH2);

    // layer 2 (XN=XH2): two S-only iterations, final writes raw fp32 x -> out+ND
    route_nodes<<<nodeBlocks, 256, 0, stream>>>(rowStart, eSrc, S, XH2, nullptr, S, nullptr);
    route_nodes<<<nodeBlocks, 256, 0, stream>>>(rowStart, eSrc, S, XH2, nullptr, S, nullptr);
    route_nodes<<<nodeBlocks, 256, 0, stream>>>(rowStart, eSrc, S, XH2, out + ND, nullptr, nullptr);

    // out = x @ mlp_w + mlp_b, reading x straight from out+ND
    gemm_plain<<<gemmBlocks, 256, 0, stream>>>(out + ND, mlp_w, mlp_b, out, flags);
}

// Round 8
// 474.401 us; speedup vs baseline: 5.0201x; 1.0473x over previous
//
#include <hip/hip_runtime.h>

#define NN 50000
#define ND (NN * 128)
#define SCAN_B 49   // ceil(NN / 1024)
#define CAP 32      // LDS-cached neighbor rows per node (Poisson(16): deg>32 is ~1e-4)

__device__ __forceinline__ float b2f(unsigned short u) {
    union { unsigned int i; float f; } v; v.i = ((unsigned int)u) << 16; return v.f;
}
__device__ __forceinline__ unsigned short f2b(float f) {      // RNE bf16 pack
    union { float f; unsigned int i; } v; v.f = f;
    return (unsigned short)((v.i + 0x7fffu + ((v.i >> 16) & 1u)) >> 16);
}
__device__ __forceinline__ unsigned int pack2(float lo, float hi) {
    return (unsigned int)f2b(lo) | ((unsigned int)f2b(hi) << 16);
}
__device__ __forceinline__ float unlo(unsigned int u) { return __uint_as_float(u << 16); }
__device__ __forceinline__ float unhi(unsigned int u) { return __uint_as_float(u & 0xFFFF0000u); }
__device__ __forceinline__ int clampi(int i, int lo, int hi) { return max(lo, min(i, hi)); }

// DPP lane ops (VALU pipe, no LDS traffic)
template<int CTRL>
__device__ __forceinline__ float dmov(float v) {
    return __int_as_float(__builtin_amdgcn_update_dpp(0, __float_as_int(v), CTRL, 0xF, 0xF, true));
}
template<int CTRL> __device__ __forceinline__ float dadd(float v) { return v + dmov<CTRL>(v); }
template<int CTRL> __device__ __forceinline__ float dmax(float v) { return fmaxf(v, dmov<CTRL>(v)); }
__device__ __forceinline__ float qsum(float v) { v = dadd<0xB1>(v); v = dadd<0x4E>(v); return v; }
__device__ __forceinline__ float rsum4(float v) { v = dadd<0x124>(v); v = dadd<0x128>(v); return v; }
__device__ __forceinline__ float rmax4(float v) { v = dmax<0x124>(v); v = dmax<0x128>(v); return v; }

// ---- dtype detection: flags[0]=1 if floats fp32; flags[1]=1 if edges int32 ----
__global__ __launch_bounds__(256) void detect(
    const unsigned short* __restrict__ feat_u, const unsigned int* __restrict__ ei_u,
    int* __restrict__ flags)
{
    int tid = threadIdx.x;
    int f32hit = 0;
    for (int i = tid; i < 8192; i += 256) {
        unsigned e = (feat_u[i] >> 7) & 0xFFu;
        if (e >= 0xC0u) f32hit = 1;
    }
    int i32hit = 0;
    for (int i = tid; i < 4096; i += 256)
        if (ei_u[2 * i + 1] != 0u) i32hit = 1;
    if (f32hit) atomicOr(&flags[0], 1);
    if (i32hit) atomicOr(&flags[1], 1);
}

// ---- extract int32 src/trg + degree histogram ----
__global__ __launch_bounds__(256) void conv_hist(
    const void* __restrict__ eiRaw, int* __restrict__ srcA, int* __restrict__ trgA,
    int* __restrict__ deg, int m, const int* __restrict__ flags)
{
    int e = blockIdx.x * 256 + threadIdx.x;
    if (e >= m) return;
    int src, trg;
    if (flags[1]) { const int* p = (const int*)eiRaw; src = p[e]; trg = p[m + e]; }
    else { const long long* p = (const long long*)eiRaw; src = (int)p[e]; trg = (int)p[m + e]; }
    src = clampi(src, 0, NN - 1);
    trg = clampi(trg, 0, NN - 1);
    srcA[e] = src; trgA[e] = trg;
    atomicAdd(&deg[trg], 1);
}

// ---- exclusive scan of deg[NN] -> rowStart[NN+1] ----
__global__ __launch_bounds__(256) void scan1(
    const int* __restrict__ deg, int* __restrict__ rowStart, int* __restrict__ blkSum)
{
    __shared__ int lds[256];
    int blk = blockIdx.x, tid = threadIdx.x;
    int base = blk * 1024 + tid * 4;
    int v[4]; int s = 0;
    #pragma unroll
    for (int j = 0; j < 4; ++j) { int idx = base + j; v[j] = (idx < NN) ? deg[idx] : 0; s += v[j]; }
    lds[tid] = s; __syncthreads();
    for (int off = 1; off < 256; off <<= 1) {
        int x = (tid >= off) ? lds[tid - off] : 0;
        __syncthreads();
        lds[tid] += x;
        __syncthreads();
    }
    int excl = lds[tid] - s;
    if (tid == 255) blkSum[blk] = lds[tid];
    int run = excl;
    #pragma unroll
    for (int j = 0; j < 4; ++j) { int idx = base + j; if (idx < NN) rowStart[idx] = run; run += v[j]; }
}
__global__ __launch_bounds__(64) void scan2(
    int* __restrict__ blkSum, int* __restrict__ blkOff, int* __restrict__ rowStart, int m)
{
    int lane = threadIdx.x;
    int orig = (lane < SCAN_B) ? blkSum[lane] : 0;
    int v = orig;
    for (int off = 1; off < 64; off <<= 1) {
        int x = __shfl_up(v, off);
        if (lane >= off) v += x;
    }
    if (lane < SCAN_B) blkOff[lane] = v - orig;
    if (lane == 0) rowStart[NN] = m;
}
__global__ __launch_bounds__(256) void scan3(int* __restrict__ rowStart, const int* __restrict__ blkOff)
{
    int base = blockIdx.x * 1024 + threadIdx.x * 4;
    int off = blkOff[blockIdx.x];
    #pragma unroll
    for (int j = 0; j < 4; ++j) { int idx = base + j; if (idx < NN) rowStart[idx] += off; }
}

// ---- scatter edges into CSR bins ----
__global__ __launch_bounds__(256) void scatter_csr(
    const int* __restrict__ srcA, const int* __restrict__ trgA,
    int* __restrict__ cursor, int* __restrict__ eSrc, int m)
{
    int e = blockIdx.x * 256 + threadIdx.x;
    if (e >= m) return;
    int pos = atomicAdd(&cursor[trgA[e]], 1);
    eSrc[pos] = srcA[e];
}

// ---- GEMM1: XNh(bf16) = channel_normalize(feat @ W + b). Raw dtypes in. ----
__global__ __launch_bounds__(256) void gemm_norm(
    const void* __restrict__ A, const void* __restrict__ W, const void* __restrict__ bias,
    unsigned short* __restrict__ XNh, const int* __restrict__ flags)
{
    __shared__ float Wl[128 * 128];
    __shared__ float As[32 * 128];
    int tid = threadIdx.x;
    int cg = tid & 31;                // cols 4cg..4cg+3
    int rg = tid >> 5;                // rows rg*4..rg*4+3 (of 32)
    int rowBase = blockIdx.x * 32;
    bool isF32 = flags[0] != 0;

    if (isF32) {
        for (int i = tid * 4; i < 128 * 128; i += 1024)
            *(float4*)&Wl[i] = *(const float4*)&((const float*)W)[i];
    } else {
        for (int i = tid * 4; i < 128 * 128; i += 1024) {
            ushort4 u = *(const ushort4*)&((const unsigned short*)W)[i];
            Wl[i] = b2f(u.x); Wl[i+1] = b2f(u.y); Wl[i+2] = b2f(u.z); Wl[i+3] = b2f(u.w);
        }
    }
    #pragma unroll
    for (int r = 0; r < 4; ++r) {
        int lrow = r * 8 + rg;
        int row = rowBase + lrow;
        float4 v = make_float4(0.f, 0.f, 0.f, 0.f);
        if (row < NN) {
            if (isF32) v = *(const float4*)&((const float*)A)[(long)row * 128 + cg * 4];
            else {
                ushort4 u = *(const ushort4*)&((const unsigned short*)A)[(long)row * 128 + cg * 4];
                v = make_float4(b2f(u.x), b2f(u.y), b2f(u.z), b2f(u.w));
            }
        }
        *(float4*)&As[lrow * 128 + cg * 4] = v;
    }
    float4 bb;
    if (isF32) bb = *(const float4*)&((const float*)bias)[cg * 4];
    else {
        ushort4 u = *(const ushort4*)&((const unsigned short*)bias)[cg * 4];
        bb = make_float4(b2f(u.x), b2f(u.y), b2f(u.z), b2f(u.w));
    }
    __syncthreads();

    float acc[4][4];
    #pragma unroll
    for (int i = 0; i < 4; ++i) { acc[i][0]=bb.x; acc[i][1]=bb.y; acc[i][2]=bb.z; acc[i][3]=bb.w; }

    for (int k4 = 0; k4 < 32; ++k4) {
        float4 w[4], av[4];
        #pragma unroll
        for (int j = 0; j < 4; ++j)
            w[j] = *(const float4*)&Wl[(k4 * 4 + j) * 128 + cg * 4];
        #pragma unroll
        for (int i = 0; i < 4; ++i)
            av[i] = *(const float4*)&As[(rg * 4 + i) * 128 + k4 * 4];
        #pragma unroll
        for (int i = 0; i < 4; ++i) {
            const float a0 = av[i].x, a1 = av[i].y, a2 = av[i].z, a3 = av[i].w;
            acc[i][0] = fmaf(a0, w[0].x, fmaf(a1, w[1].x, fmaf(a2, w[2].x, fmaf(a3, w[3].x, acc[i][0]))));
            acc[i][1] = fmaf(a0, w[0].y, fmaf(a1, w[1].y, fmaf(a2, w[2].y, fmaf(a3, w[3].y, acc[i][1]))));
            acc[i][2] = fmaf(a0, w[0].z, fmaf(a1, w[1].z, fmaf(a2, w[2].z, fmaf(a3, w[3].z, acc[i][2]))));
            acc[i][3] = fmaf(a0, w[0].w, fmaf(a1, w[1].w, fmaf(a2, w[2].w, fmaf(a3, w[3].w, acc[i][3]))));
        }
    }
    #pragma unroll
    for (int i = 0; i < 4; ++i) {
        int row = rowBase + rg * 4 + i;
        float lss = acc[i][0]*acc[i][0] + acc[i][1]*acc[i][1] + acc[i][2]*acc[i][2] + acc[i][3]*acc[i][3];
        lss += __shfl_xor(lss, 1);
        lss += __shfl_xor(lss, 2);
        lss += __shfl_xor(lss, 4);
        float scale = 1.0f / fmaxf(sqrtf(lss), 1e-12f);
        if (row < NN) {
            float4 o; o.x = acc[i][0]*scale; o.y = acc[i][1]*scale; o.z = acc[i][2]*scale; o.w = acc[i][3]*scale;
            uint2 pk; pk.x = pack2(o.x, o.y); pk.y = pack2(o.z, o.w);
            *(uint2*)((char*)XNh + (long)row * 256 + cg * 8) = pk;
        }
    }
}

// ---- GEMM2: Out = A @ W + b (A fp32) ----
__global__ __launch_bounds__(256) void gemm_plain(
    const float* __restrict__ A, const void* __restrict__ W, const void* __restrict__ bias,
    float* __restrict__ Out, const int* __restrict__ flags)
{
    __shared__ float Wl[128 * 128];
    __shared__ float As[32 * 128];
    int tid = threadIdx.x;
    int cg = tid & 31;
    int rg = tid >> 5;
    int rowBase = blockIdx.x * 32;
    bool isF32 = flags[0] != 0;

    if (isF32) {
        for (int i = tid * 4; i < 128 * 128; i += 1024)
            *(float4*)&Wl[i] = *(const float4*)&((const float*)W)[i];
    } else {
        for (int i = tid * 4; i < 128 * 128; i += 1024) {
            ushort4 u = *(const ushort4*)&((const unsigned short*)W)[i];
            Wl[i] = b2f(u.x); Wl[i+1] = b2f(u.y); Wl[i+2] = b2f(u.z); Wl[i+3] = b2f(u.w);
        }
    }
    #pragma unroll
    for (int r = 0; r < 4; ++r) {
        int lrow = r * 8 + rg;
        int row = rowBase + lrow;
        float4 v = make_float4(0.f, 0.f, 0.f, 0.f);
        if (row < NN) v = *(const float4*)&A[(long)row * 128 + cg * 4];
        *(float4*)&As[lrow * 128 + cg * 4] = v;
    }
    float4 bb;
    if (isF32) bb = *(const float4*)&((const float*)bias)[cg * 4];
    else {
        ushort4 u = *(const ushort4*)&((const unsigned short*)bias)[cg * 4];
        bb = make_float4(b2f(u.x), b2f(u.y), b2f(u.z), b2f(u.w));
    }
    __syncthreads();

    float acc[4][4];
    #pragma unroll
    for (int i = 0; i < 4; ++i) { acc[i][0]=bb.x; acc[i][1]=bb.y; acc[i][2]=bb.z; acc[i][3]=bb.w; }

    for (int k4 = 0; k4 < 32; ++k4) {
        float4 w[4], av[4];
        #pragma unroll
        for (int j = 0; j < 4; ++j)
            w[j] = *(const float4*)&Wl[(k4 * 4 + j) * 128 + cg * 4];
        #pragma unroll
        for (int i = 0; i < 4; ++i)
            av[i] = *(const float4*)&As[(rg * 4 + i) * 128 + k4 * 4];
        #pragma unroll
        for (int i = 0; i < 4; ++i) {
            const float a0 = av[i].x, a1 = av[i].y, a2 = av[i].z, a3 = av[i].w;
            acc[i][0] = fmaf(a0, w[0].x, fmaf(a1, w[1].x, fmaf(a2, w[2].x, fmaf(a3, w[3].x, acc[i][0]))));
            acc[i][1] = fmaf(a0, w[0].y, fmaf(a1, w[1].y, fmaf(a2, w[2].y, fmaf(a3, w[3].y, acc[i][1]))));
            acc[i][2] = fmaf(a0, w[0].z, fmaf(a1, w[1].z, fmaf(a2, w[2].z, fmaf(a3, w[3].z, acc[i][2]))));
            acc[i][3] = fmaf(a0, w[0].w, fmaf(a1, w[1].w, fmaf(a2, w[2].w, fmaf(a3, w[3].w, acc[i][3]))));
        }
    }
    #pragma unroll
    for (int i = 0; i < 4; ++i) {
        int row = rowBase + rg * 4 + i;
        if (row < NN) {
            float4 o; o.x = acc[i][0]; o.y = acc[i][1]; o.z = acc[i][2]; o.w = acc[i][3];
            *(float4*)&Out[(long)row * 128 + cg * 4] = o;
        }
    }
}

// ---- fused per-layer routing: 1 wave/node, all 3 iterations, z staged in LDS ----
// Layer output: XNOut (bf16 normalized, layer 1) or CT (fp32 raw, layer 2).
__global__ __launch_bounds__(256) void route_layer(
    const int* __restrict__ rowStart, const int* __restrict__ eSrc,
    const unsigned short* __restrict__ XNh,
    unsigned short* __restrict__ XNOut, float* __restrict__ CT)
{
    __shared__ unsigned short zbuf[4][CAP * 128];   // 32 KB
    int w = threadIdx.x >> 6;
    int node = blockIdx.x * 4 + w;                  // NN % 4 == 0: always valid
    int lane = threadIdx.x & 63;
    int slot = lane >> 4;                           // 4 edge slots
    int h = lane & 15;                              // elems 8h..8h+7, channel h>>2
    int beg = rowStart[node], end = rowStart[node + 1];
    int deg = end - beg;
    int degL = min(deg, CAP);
    const char* XNb = (const char*)XNh;

    // stage neighbor z rows into LDS: 16 lanes per row, 4 rows per pass
    for (int r = slot; r < degL; r += 4) {
        int src = eSrc[beg + r];
        uint4 v = *(const uint4*)(XNb + ((long)src * 256 + h * 16));
        *(uint4*)&zbuf[w][r * 128 + h * 8] = v;
    }
    // residual xn row (same address for all 4 slots -> L1 broadcast)
    uint4 xr = *(const uint4*)(XNb + ((long)node * 256 + h * 16));
    float x0 = unlo(xr.x), x1 = unhi(xr.x), x2 = unlo(xr.y), x3 = unhi(xr.y);
    float x4 = unlo(xr.z), x5 = unhi(xr.z), x6 = unlo(xr.w), x7 = unhi(xr.w);
    // initial s from xn (already channel-normalized): s_{2h}=tx, s_{2h+1}=ty
    float tx = x0 + x1 + x2 + x3;
    float ty = x4 + x5 + x6 + x7;
    int sb = (lane & 48) | (4 * (h & 3));           // slot base + 4*(channel-pos)
    float4 sA, sB;
    sA.x = __shfl(tx, sb);     sA.y = __shfl(ty, sb);
    sA.z = __shfl(tx, sb + 1); sA.w = __shfl(ty, sb + 1);
    sB.x = __shfl(tx, sb + 2); sB.y = __shfl(ty, sb + 2);
    sB.z = __shfl(tx, sb + 3); sB.w = __shfl(ty, sb + 3);
    __syncthreads();

    float4 aA, aB;
    #pragma unroll
    for (int iter = 0; iter < 3; ++iter) {
        if (slot == 0) { aA = make_float4(x0, x1, x2, x3); aB = make_float4(x4, x5, x6, x7); }
        else { aA = make_float4(0.f, 0.f, 0.f, 0.f); aB = aA; }
        for (int i = slot; i < deg; i += 4) {
            uint4 zu;
            if (i < CAP) zu = *(const uint4*)&zbuf[w][i * 128 + h * 8];
            else         zu = *(const uint4*)(XNb + ((long)eSrc[beg + i] * 256 + h * 16));
            float z0 = unlo(zu.x), z1 = unhi(zu.x), z2 = unlo(zu.y), z3 = unhi(zu.y);
            float z4 = unlo(zu.z), z5 = unhi(zu.z), z6 = unlo(zu.w), z7 = unhi(zu.w);
            float p = fmaf(z0, sA.x, fmaf(z1, sA.y, fmaf(z2, sA.z, fmaf(z3, sA.w,
                      fmaf(z4, sB.x, fmaf(z5, sB.y, fmaf(z6, sB.z, z7 * sB.w)))))));
            p = qsum(p);                            // p_k within quad (channel)
            float mx = rmax4(p);                    // softmax across 4 channels
            float ex = __expf(p - mx);
            float sm = rsum4(ex);
            float wgt = ex * __builtin_amdgcn_rcpf(sm);
            aA.x = fmaf(wgt, z0, aA.x); aA.y = fmaf(wgt, z1, aA.y);
            aA.z = fmaf(wgt, z2, aA.z); aA.w = fmaf(wgt, z3, aA.w);
            aB.x = fmaf(wgt, z4, aB.x); aB.y = fmaf(wgt, z5, aB.y);
            aB.z = fmaf(wgt, z6, aB.z); aB.w = fmaf(wgt, z7, aB.w);
        }
        // combine 4 slots -> every lane holds full c[8h..8h+7]
        aA.x += __shfl_xor(aA.x, 16); aA.x += __shfl_xor(aA.x, 32);
        aA.y += __shfl_xor(aA.y, 16); aA.y += __shfl_xor(aA.y, 32);
        aA.z += __shfl_xor(aA.z, 16); aA.z += __shfl_xor(aA.z, 32);
        aA.w += __shfl_xor(aA.w, 16); aA.w += __shfl_xor(aA.w, 32);
        aB.x += __shfl_xor(aB.x, 16); aB.x += __shfl_xor(aB.x, 32);
        aB.y += __shfl_xor(aB.y, 16); aB.y += __shfl_xor(aB.y, 32);
        aB.z += __shfl_xor(aB.z, 16); aB.z += __shfl_xor(aB.z, 32);
        aB.w += __shfl_xor(aB.w, 16); aB.w += __shfl_xor(aB.w, 32);
        if (iter < 2) {
            // normalize in-register, derive next s, redistribute via shfl
            float ssq = aA.x*aA.x + aA.y*aA.y + aA.z*aA.z + aA.w*aA.w
                      + aB.x*aB.x + aB.y*aB.y + aB.z*aB.z + aB.w*aB.w;
            ssq = qsum(ssq);
            float scale = 1.0f / fmaxf(sqrtf(ssq), 1e-12f);
            tx = (aA.x + aA.y + aA.z + aA.w) * scale;
            ty = (aB.x + aB.y + aB.z + aB.w) * scale;
            sA.x = __shfl(tx, sb);     sA.y = __shfl(ty, sb);
            sA.z = __shfl(tx, sb + 1); sA.w = __shfl(ty, sb + 1);
            sB.x = __shfl(tx, sb + 2); sB.y = __shfl(ty, sb + 2);
            sB.z = __shfl(tx, sb + 3); sB.w = __shfl(ty, sb + 3);
        }
    }
    // epilogue
    if (XNOut) {   // layer 1: write channel-normalized bf16 (next layer's xn)
        float ssq = aA.x*aA.x + aA.y*aA.y + aA.z*aA.z + aA.w*aA.w
                  + aB.x*aB.x + aB.y*aB.y + aB.z*aB.z + aB.w*aB.w;
        ssq = qsum(ssq);
        float scale = 1.0f / fmaxf(sqrtf(ssq), 1e-12f);
        if (slot == 0) {
            uint4 pk;
            pk.x = pack2(aA.x * scale, aA.y * scale);
            pk.y = pack2(aA.z * scale, aA.w * scale);
            pk.z = pack2(aB.x * scale, aB.y * scale);
            pk.w = pack2(aB.z * scale, aB.w * scale);
            *(uint4*)((char*)XNOut + ((long)node * 256 + h * 16)) = pk;
        }
    }
    if (CT && slot == 0) {   // layer 2: raw fp32 x
        float4* cp = (float4*)(CT + (long)node * 128 + 8 * h);
        cp[0] = aA; cp[1] = aB;
    }
}

extern "C" void kernel_launch(void* const* d_in, const int* in_sizes, int n_in,
                              void* d_out, int out_size, void* d_ws, size_t ws_size,
                              hipStream_t stream) {
    const void* feat  = d_in[0];
    const void* ei    = d_in[1];
    const void* lin_w = d_in[2];
    const void* lin_b = d_in[3];
    const void* mlp_w = d_in[4];
    const void* mlp_b = d_in[5];
    float* out = (float*)d_out;               // [out(N,128) | x(N,128)] fp32

    const int m = in_sizes[1] / 2;            // 800000 edges

    // ---- workspace layout ----
    char* wsB = (char*)d_ws;
    int*   flags = (int*)wsB;                                  // 256 B slot
    unsigned short* XH1 = (unsigned short*)(wsB + 256);        // NN*128 bf16
    unsigned short* XH2 = XH1 + ND;                            // NN*128 bf16
    int*   srcA  = (int*)(XH2 + ND);                           // m
    int*   trgA  = srcA + m;                                   // m
    int*   eSrc  = trgA + m;                                   // m
    int*   deg   = eSrc + m;                                   // NN
    int*   rowStart = deg + NN;                                // NN+1
    int*   cursor   = rowStart + NN + 1;                       // NN
    int*   blkSum   = cursor + NN;                             // 64
    int*   blkOff   = blkSum + 64;                             // 64

    hipMemsetAsync(flags, 0, 8, stream);
    hipMemsetAsync(deg, 0, NN * sizeof(int), stream);
    detect<<<1, 256, 0, stream>>>((const unsigned short*)feat, (const unsigned int*)ei, flags);

    const int edgeBlocks = (m + 255) / 256;
    conv_hist<<<edgeBlocks, 256, 0, stream>>>(ei, srcA, trgA, deg, m, flags);
    scan1<<<SCAN_B, 256, 0, stream>>>(deg, rowStart, blkSum);
    scan2<<<1, 64, 0, stream>>>(blkSum, blkOff, rowStart, m);
    scan3<<<SCAN_B, 256, 0, stream>>>(rowStart, blkOff);
    hipMemcpyAsync(cursor, rowStart, NN * sizeof(int), hipMemcpyDeviceToDevice, stream);
    scatter_csr<<<edgeBlocks, 256, 0, stream>>>(srcA, trgA, cursor, eSrc, m);

    const int gemmBlocks = (NN + 31) / 32;
    const int nodeBlocks = NN / 4;            // NN % 4 == 0

    // gemm1 + fused normalize: feat -> XH1 (bf16)
    gemm_norm<<<gemmBlocks, 256, 0, stream>>>(feat, lin_w, lin_b, XH1, flags);

    // layer 1: all 3 routing iterations fused; writes normalized bf16 XH2
    route_layer<<<nodeBlocks, 256, 0, stream>>>(rowStart, eSrc, XH1, XH2, nullptr);
    // layer 2: writes raw fp32 x -> out+ND
    route_layer<<<nodeBlocks, 256, 0, stream>>>(rowStart, eSrc, XH2, nullptr, out + ND);

    // out = x @ mlp_w + mlp_b, reading x straight from out+ND
    gemm_plain<<<gemmBlocks, 256, 0, stream>>>(out + ND, mlp_w, mlp_b, out, flags);
}